// Round 1
// baseline (552.007 us; speedup 1.0000x reference)
//
#include <hip/hip_runtime.h>
#include <math.h>

#define SLEN 2000
#define BATCH 8
#define MTOK 16000
#define WIN 99

enum { EPI_NONE = 0, EPI_POSENC = 1, EPI_RELU = 2, EPI_RESID = 3 };

// ---------------- positional encoding table [SLEN][256] ----------------
__global__ __launch_bounds__(256) void k_posenc(float* __restrict__ pe) {
  int idx = blockIdx.x * 256 + threadIdx.x;   // [0, SLEN*256)
  int s = idx >> 8;
  int d = idx & 255;
  int p = d >> 1;
  float dv  = expf((float)p * -0.07195578415606394f);  // exp(-p*ln(10000)/128)
  float ang = (float)s * dv;
  pe[idx] = (d & 1) ? cosf(ang) : sinf(ang);
}

// ---- GEMM: Y[M,N] = X[M,256] @ W[N,256]^T + bias, fused epilogue ----
// block = 256 threads, tile = 128 tokens x 128 outputs, thread = 8x8 regs.
// Thread (ty,tx) owns tokens {ty*4..+3, 64+ty*4..+3}, outs {tx*4..+3, 64+tx*4..+3}
// (split-half mapping keeps LDS reads at <=2-way bank aliasing, which is free).
__global__ __launch_bounds__(256) void k_gemm(const float* __restrict__ X,
                                              const float* __restrict__ W,
                                              const float* __restrict__ bias,
                                              float* __restrict__ Y,
                                              const float* __restrict__ extra,
                                              int N, int mode) {
  __shared__ float xsT[16][132];   // [k][token], +4 pad
  __shared__ float wsT[16][132];   // [k][out]
  const int tid = threadIdx.x;
  const int tx = tid & 15, ty = tid >> 4;
  const int m0 = blockIdx.x * 128;
  const int o0 = blockIdx.y * 128;

  float acc[8][8];
#pragma unroll
  for (int i = 0; i < 8; ++i)
#pragma unroll
    for (int j = 0; j < 8; ++j) acc[i][j] = 0.f;

  for (int kt = 0; kt < 256; kt += 16) {
    __syncthreads();
    // stage X tile [128 tok][16 k] and W tile [128 out][16 k], transposed
#pragma unroll
    for (int rep = 0; rep < 2; ++rep) {
      int idx = tid + rep * 256;        // 0..511
      int r   = idx >> 2;               // 0..127
      int c4  = (idx & 3) * 4;          // 0,4,8,12
      float4 v = *(const float4*)(X + (size_t)(m0 + r) * 256 + kt + c4);
      xsT[c4 + 0][r] = v.x; xsT[c4 + 1][r] = v.y;
      xsT[c4 + 2][r] = v.z; xsT[c4 + 3][r] = v.w;
      float4 wv = *(const float4*)(W + (size_t)(o0 + r) * 256 + kt + c4);
      wsT[c4 + 0][r] = wv.x; wsT[c4 + 1][r] = wv.y;
      wsT[c4 + 2][r] = wv.z; wsT[c4 + 3][r] = wv.w;
    }
    __syncthreads();
#pragma unroll
    for (int kk = 0; kk < 16; ++kk) {
      float4 a0 = *(const float4*)&xsT[kk][ty * 4];
      float4 a1 = *(const float4*)&xsT[kk][64 + ty * 4];
      float4 b0 = *(const float4*)&wsT[kk][tx * 4];
      float4 b1 = *(const float4*)&wsT[kk][64 + tx * 4];
      float av[8] = {a0.x, a0.y, a0.z, a0.w, a1.x, a1.y, a1.z, a1.w};
      float bv[8] = {b0.x, b0.y, b0.z, b0.w, b1.x, b1.y, b1.z, b1.w};
#pragma unroll
      for (int i = 0; i < 8; ++i)
#pragma unroll
        for (int j = 0; j < 8; ++j) acc[i][j] += av[i] * bv[j];
    }
  }

  // epilogue
#pragma unroll
  for (int ih = 0; ih < 2; ++ih) {
#pragma unroll
    for (int i4 = 0; i4 < 4; ++i4) {
      int m    = m0 + ih * 64 + ty * 4 + i4;
      int srow = m % SLEN;
#pragma unroll
      for (int jh = 0; jh < 2; ++jh) {
        int oc = o0 + jh * 64 + tx * 4;     // global col of this float4
        float4 r;
        r.x = acc[ih * 4 + i4][jh * 4 + 0];
        r.y = acc[ih * 4 + i4][jh * 4 + 1];
        r.z = acc[ih * 4 + i4][jh * 4 + 2];
        r.w = acc[ih * 4 + i4][jh * 4 + 3];
        float4 bb = *(const float4*)&bias[oc];
        r.x += bb.x; r.y += bb.y; r.z += bb.z; r.w += bb.w;
        if (mode == EPI_POSENC) {
          float4 p = *(const float4*)&extra[(size_t)srow * 256 + oc];
          r.x += p.x; r.y += p.y; r.z += p.z; r.w += p.w;
        } else if (mode == EPI_RELU) {
          r.x = fmaxf(r.x, 0.f); r.y = fmaxf(r.y, 0.f);
          r.z = fmaxf(r.z, 0.f); r.w = fmaxf(r.w, 0.f);
        } else if (mode == EPI_RESID) {
          float4 p = *(const float4*)&extra[(size_t)m * 256 + oc];
          r.x += p.x; r.y += p.y; r.z += p.z; r.w += p.w;
        }
        *(float4*)&Y[(size_t)m * N + oc] = r;
      }
    }
  }
}

// ---------------- banded attention ----------------
// grid (S/16, B, H), block 256. 16 queries/block, window union <= 115 keys.
// qkv layout: [b][s][768], q at +0, k at +256, v at +512, head h at +h*128.
__global__ __launch_bounds__(256) void k_attn(const float* __restrict__ qkv,
                                              float* __restrict__ ctx) {
  __shared__ float Qs[16][132];
  __shared__ float Ks[32][132];          // also reused for V chunks
  __shared__ float ps[16][128];
  __shared__ float rinv[16];
  const int tid = threadIdx.x;
  const int i0  = blockIdx.x * 16;
  const int b   = blockIdx.y;
  const int h   = blockIdx.z;

  const int jmin = max(0, i0 - WIN);
  const int jmax = i0 + 15;
  const int cnt  = jmax - jmin + 1;            // <= 115
  const int cntR = (cnt + 3) & ~3;

  // load Q tile
  {
    int r = tid >> 4;
    int c = (tid & 15) * 8;
    const float* srcq = qkv + ((size_t)(b * SLEN + i0 + r)) * 768 + h * 128 + c;
    float4 v0 = *(const float4*)(srcq);
    float4 v1 = *(const float4*)(srcq + 4);
    *(float4*)&Qs[r][c]     = v0;
    *(float4*)&Qs[r][c + 4] = v1;
  }

  const float scale = 0.08838834764831845f;    // 1/sqrt(128)

  // ---- scores ----
  for (int jb = 0; jb < cnt; jb += 32) {
    __syncthreads();
    for (int idx = tid * 4; idx < 32 * 128; idx += 1024) {
      int r = idx >> 7, c = idx & 127;
      int j = jmin + jb + r;
      float4 v = (j <= jmax)
        ? *(const float4*)(qkv + ((size_t)(b * SLEN + j)) * 768 + 256 + h * 128 + c)
        : make_float4(0.f, 0.f, 0.f, 0.f);
      *(float4*)&Ks[r][c] = v;
    }
    __syncthreads();
    int qi = tid >> 4;
    int i  = i0 + qi;
#pragma unroll
    for (int half = 0; half < 2; ++half) {
      int jj = (tid & 15) + half * 16;
      int j  = jmin + jb + jj;
      float s = -1e30f;
      if (j <= i && j >= i - WIN) {
        float a = 0.f;
#pragma unroll
        for (int kk = 0; kk < 128; kk += 4) {
          float4 qv = *(const float4*)&Qs[qi][kk];
          float4 kv = *(const float4*)&Ks[jj][kk];
          a += qv.x * kv.x + qv.y * kv.y + qv.z * kv.z + qv.w * kv.w;
        }
        s = a * scale;
      }
      ps[qi][jb + jj] = s;
    }
  }
  __syncthreads();

  // ---- softmax (16 lanes per row, contiguous within a wave) ----
  {
    int r = tid >> 4, sub = tid & 15;
    float m = -1e30f;
    for (int j = sub; j < cntR; j += 16) m = fmaxf(m, ps[r][j]);
#pragma unroll
    for (int off = 8; off; off >>= 1) m = fmaxf(m, __shfl_xor(m, off, 16));
    float sum = 0.f;
    for (int j = sub; j < cntR; j += 16) {
      float e = __expf(ps[r][j] - m);
      ps[r][j] = e;
      sum += e;
    }
#pragma unroll
    for (int off = 8; off; off >>= 1) sum += __shfl_xor(sum, off, 16);
    if (sub == 0) rinv[r] = 1.f / sum;
  }

  // ---- P @ V ----
  float acc[8];
#pragma unroll
  for (int q = 0; q < 8; ++q) acc[q] = 0.f;
  int d     = tid & 127;
  int qbase = (tid >> 7) * 8;
  for (int jb = 0; jb < cnt; jb += 32) {
    __syncthreads();
    for (int idx = tid * 4; idx < 32 * 128; idx += 1024) {
      int r = idx >> 7, c = idx & 127;
      int j = jmin + jb + r;
      float4 v = (j <= jmax)
        ? *(const float4*)(qkv + ((size_t)(b * SLEN + j)) * 768 + 512 + h * 128 + c)
        : make_float4(0.f, 0.f, 0.f, 0.f);
      *(float4*)&Ks[r][c] = v;
    }
    __syncthreads();
    int jcnt = min(32, cntR - jb);               // multiple of 4
    for (int jj = 0; jj < jcnt; jj += 4) {
      float v0 = Ks[jj + 0][d], v1 = Ks[jj + 1][d];
      float v2 = Ks[jj + 2][d], v3 = Ks[jj + 3][d];
#pragma unroll
      for (int q = 0; q < 8; ++q) {
        float4 p = *(const float4*)&ps[qbase + q][jb + jj];
        acc[q] += p.x * v0 + p.y * v1 + p.z * v2 + p.w * v3;
      }
    }
  }
#pragma unroll
  for (int q = 0; q < 8; ++q) {
    int i = i0 + qbase + q;
    ctx[((size_t)(b * SLEN + i)) * 256 + h * 128 + d] = acc[q] * rinv[qbase + q];
  }
}

// ---------------- layernorm in-place over D=256, one block per token ----
__global__ __launch_bounds__(256) void k_ln(float* __restrict__ X,
                                            const float* __restrict__ w,
                                            const float* __restrict__ b) {
  __shared__ float red[8];
  int m = blockIdx.x, tid = threadIdx.x;
  float v = X[(size_t)m * 256 + tid];
  float s = v, q = v * v;
#pragma unroll
  for (int off = 32; off; off >>= 1) {
    s += __shfl_xor(s, off);
    q += __shfl_xor(q, off);
  }
  int wv = tid >> 6;
  if ((tid & 63) == 0) { red[wv] = s; red[4 + wv] = q; }
  __syncthreads();
  s = red[0] + red[1] + red[2] + red[3];
  q = red[4] + red[5] + red[6] + red[7];
  float mu  = s * (1.f / 256.f);
  float var = q * (1.f / 256.f) - mu * mu;
  float r   = rsqrtf(var + 1e-5f);
  X[(size_t)m * 256 + tid] = (v - mu) * r * w[tid] + b[tid];
}

// ---------------- head: logits[m] = (x@fc1^T+b1) @ fc2^T + b2 ----------
// block 256 = 4 waves, one token per wave, lane = fc1 output channel.
__global__ __launch_bounds__(256) void k_head(const float* __restrict__ X,
                                              const float* __restrict__ fc1w,
                                              const float* __restrict__ fc1b,
                                              const float* __restrict__ fc2w,
                                              const float* __restrict__ fc2b,
                                              float* __restrict__ out) {
  __shared__ float xs[4][256];
  int tid = threadIdx.x;
  int m0  = blockIdx.x * 4;
  {
    int r = tid >> 6, c4 = (tid & 63) * 4;
    *(float4*)&xs[r][c4] = *(const float4*)(X + (size_t)(m0 + r) * 256 + c4);
  }
  __syncthreads();
  int w = tid >> 6;
  int o = tid & 63;
  const float* wr = fc1w + (size_t)o * 256;
  float a = 0.f;
#pragma unroll
  for (int k = 0; k < 256; k += 4) {
    float4 wv = *(const float4*)(wr + k);
    a += xs[w][k] * wv.x + xs[w][k + 1] * wv.y + xs[w][k + 2] * wv.z + xs[w][k + 3] * wv.w;
  }
  a += fc1b[o];
  float part = a * fc2w[o];
#pragma unroll
  for (int off = 32; off; off >>= 1) part += __shfl_xor(part, off);
  if (o == 0) out[m0 + w] = part + fc2b[0];
}

extern "C" void kernel_launch(void* const* d_in, const int* in_sizes, int n_in,
                              void* d_out, int out_size, void* d_ws, size_t ws_size,
                              hipStream_t stream) {
  const float* src        = (const float*)d_in[0];
  // d_in[1] = input_lengths (int64) — unused by the reference computation
  const float* W_enc      = (const float*)d_in[2];
  const float* b_enc      = (const float*)d_in[3];
  const float* in_proj_w  = (const float*)d_in[4];
  const float* in_proj_b  = (const float*)d_in[5];
  const float* out_proj_w = (const float*)d_in[6];
  const float* out_proj_b = (const float*)d_in[7];
  const float* ln1_w      = (const float*)d_in[8];
  const float* ln1_b      = (const float*)d_in[9];
  const float* lin1_w     = (const float*)d_in[10];
  const float* lin1_b     = (const float*)d_in[11];
  const float* lin2_w     = (const float*)d_in[12];
  const float* lin2_b     = (const float*)d_in[13];
  const float* ln2_w      = (const float*)d_in[14];
  const float* ln2_b      = (const float*)d_in[15];
  const float* fc1_w      = (const float*)d_in[16];
  const float* fc1_b      = (const float*)d_in[17];
  const float* fc2_w      = (const float*)d_in[18];
  const float* fc2_b      = (const float*)d_in[19];

  float* ws  = (float*)d_ws;
  float* x   = ws;                      // [16000][256]
  float* qkv = x + (size_t)MTOK * 256;  // [16000][768]   (later reused as x1)
  float* ctx = qkv + (size_t)MTOK * 768;// [16000][256]   (later reused as ffn hidden)
  float* pe  = ctx + (size_t)MTOK * 256;// [2000][256]
  // total: 20,992,000 floats = ~84 MB of d_ws

  k_posenc<<<SLEN * 256 / 256, 256, 0, stream>>>(pe);
  // x = src @ W_enc^T + b_enc + posenc
  k_gemm<<<dim3(MTOK / 128, 2), 256, 0, stream>>>(src, W_enc, b_enc, x, pe, 256, EPI_POSENC);
  // qkv = x @ in_proj^T + b
  k_gemm<<<dim3(MTOK / 128, 6), 256, 0, stream>>>(x, in_proj_w, in_proj_b, qkv, nullptr, 768, EPI_NONE);
  // banded attention -> ctx
  k_attn<<<dim3(SLEN / 16, BATCH, 2), 256, 0, stream>>>(qkv, ctx);
  // pre-LN1 = ctx @ out_proj^T + b + x   (written into qkv buffer, reused as x1)
  k_gemm<<<dim3(MTOK / 128, 2), 256, 0, stream>>>(ctx, out_proj_w, out_proj_b, qkv, x, 256, EPI_RESID);
  k_ln<<<MTOK, 256, 0, stream>>>(qkv, ln1_w, ln1_b);                 // x1 (in-place)
  // h = relu(x1 @ lin1^T + b)  -> ctx buffer
  k_gemm<<<dim3(MTOK / 128, 2), 256, 0, stream>>>(qkv, lin1_w, lin1_b, ctx, nullptr, 256, EPI_RELU);
  // pre-LN2 = h @ lin2^T + b + x1 -> x buffer
  k_gemm<<<dim3(MTOK / 128, 2), 256, 0, stream>>>(ctx, lin2_w, lin2_b, x, qkv, 256, EPI_RESID);
  k_ln<<<MTOK, 256, 0, stream>>>(x, ln2_w, ln2_b);                   // x2 (in-place)
  // head
  k_head<<<MTOK / 4, 256, 0, stream>>>(x, fc1_w, fc1_b, fc2_w, fc2_b, (float*)d_out);
}

// Round 2
// 422.184 us; speedup vs baseline: 1.3075x; 1.3075x over previous
//
#include <hip/hip_runtime.h>
#include <math.h>

#define SLEN 2000
#define BATCH 8
#define MTOK 16000
#define WIN 99

enum { EPI_NONE = 0, EPI_POSENC = 1, EPI_RELU = 2, EPI_RESID = 3 };

// ---------------- positional encoding table [SLEN][256] ----------------
__global__ __launch_bounds__(256) void k_posenc(float* __restrict__ pe) {
  int idx = blockIdx.x * 256 + threadIdx.x;   // [0, SLEN*256)
  int s = idx >> 8;
  int d = idx & 255;
  int p = d >> 1;
  float dv  = expf((float)p * -0.07195578415606394f);  // exp(-p*ln(10000)/128)
  float ang = (float)s * dv;
  pe[idx] = (d & 1) ? cosf(ang) : sinf(ang);
}

// ---- GEMM: Y[M,N] = X[M,256] @ W[N,256]^T + bias, fused epilogue ----
// block = 256 threads, tile = 128 tokens x 128 outputs, thread = 8x8 regs.
__global__ __launch_bounds__(256) void k_gemm(const float* __restrict__ X,
                                              const float* __restrict__ W,
                                              const float* __restrict__ bias,
                                              float* __restrict__ Y,
                                              const float* __restrict__ extra,
                                              int N, int mode) {
  __shared__ float xsT[16][132];   // [k][token], +4 pad
  __shared__ float wsT[16][132];   // [k][out]
  const int tid = threadIdx.x;
  const int tx = tid & 15, ty = tid >> 4;
  const int m0 = blockIdx.x * 128;
  const int o0 = blockIdx.y * 128;

  float acc[8][8];
#pragma unroll
  for (int i = 0; i < 8; ++i)
#pragma unroll
    for (int j = 0; j < 8; ++j) acc[i][j] = 0.f;

  for (int kt = 0; kt < 256; kt += 16) {
    __syncthreads();
    // stage X tile [128 tok][16 k] and W tile [128 out][16 k], transposed
#pragma unroll
    for (int rep = 0; rep < 2; ++rep) {
      int idx = tid + rep * 256;        // 0..511
      int r   = idx >> 2;               // 0..127
      int c4  = (idx & 3) * 4;          // 0,4,8,12
      float4 v = *(const float4*)(X + (size_t)(m0 + r) * 256 + kt + c4);
      xsT[c4 + 0][r] = v.x; xsT[c4 + 1][r] = v.y;
      xsT[c4 + 2][r] = v.z; xsT[c4 + 3][r] = v.w;
      float4 wv = *(const float4*)(W + (size_t)(o0 + r) * 256 + kt + c4);
      wsT[c4 + 0][r] = wv.x; wsT[c4 + 1][r] = wv.y;
      wsT[c4 + 2][r] = wv.z; wsT[c4 + 3][r] = wv.w;
    }
    __syncthreads();
#pragma unroll
    for (int kk = 0; kk < 16; ++kk) {
      float4 a0 = *(const float4*)&xsT[kk][ty * 4];
      float4 a1 = *(const float4*)&xsT[kk][64 + ty * 4];
      float4 b0 = *(const float4*)&wsT[kk][tx * 4];
      float4 b1 = *(const float4*)&wsT[kk][64 + tx * 4];
      float av[8] = {a0.x, a0.y, a0.z, a0.w, a1.x, a1.y, a1.z, a1.w};
      float bv[8] = {b0.x, b0.y, b0.z, b0.w, b1.x, b1.y, b1.z, b1.w};
#pragma unroll
      for (int i = 0; i < 8; ++i)
#pragma unroll
        for (int j = 0; j < 8; ++j) acc[i][j] += av[i] * bv[j];
    }
  }

  // epilogue
#pragma unroll
  for (int ih = 0; ih < 2; ++ih) {
#pragma unroll
    for (int i4 = 0; i4 < 4; ++i4) {
      int m    = m0 + ih * 64 + ty * 4 + i4;
      int srow = m % SLEN;
#pragma unroll
      for (int jh = 0; jh < 2; ++jh) {
        int oc = o0 + jh * 64 + tx * 4;     // global col of this float4
        float4 r;
        r.x = acc[ih * 4 + i4][jh * 4 + 0];
        r.y = acc[ih * 4 + i4][jh * 4 + 1];
        r.z = acc[ih * 4 + i4][jh * 4 + 2];
        r.w = acc[ih * 4 + i4][jh * 4 + 3];
        float4 bb = *(const float4*)&bias[oc];
        r.x += bb.x; r.y += bb.y; r.z += bb.z; r.w += bb.w;
        if (mode == EPI_POSENC) {
          float4 p = *(const float4*)&extra[(size_t)srow * 256 + oc];
          r.x += p.x; r.y += p.y; r.z += p.z; r.w += p.w;
        } else if (mode == EPI_RELU) {
          r.x = fmaxf(r.x, 0.f); r.y = fmaxf(r.y, 0.f);
          r.z = fmaxf(r.z, 0.f); r.w = fmaxf(r.w, 0.f);
        } else if (mode == EPI_RESID) {
          float4 p = *(const float4*)&extra[(size_t)m * 256 + oc];
          r.x += p.x; r.y += p.y; r.z += p.z; r.w += p.w;
        }
        *(float4*)&Y[(size_t)m * N + oc] = r;
      }
    }
  }
}

// ---------------- banded attention ----------------
// grid (S/16, B, H), block 256. 16 queries/block, window union <= 115 keys.
// qkv layout: [b][s][768], q at +0, k at +256, v at +512, head h at +h*128.
__global__ __launch_bounds__(256) void k_attn(const float* __restrict__ qkv,
                                              float* __restrict__ ctx) {
  __shared__ float Qs[16][132];
  __shared__ float Ks[32][132];          // also reused for V chunks
  __shared__ float ps[16][128];
  __shared__ float rinv[16];
  const int tid = threadIdx.x;
  const int i0  = blockIdx.x * 16;
  const int b   = blockIdx.y;
  const int h   = blockIdx.z;

  const int jmin = max(0, i0 - WIN);
  const int jmax = i0 + 15;
  const int cnt  = jmax - jmin + 1;            // <= 115
  const int cntR = (cnt + 3) & ~3;

  // load Q tile
  {
    int r = tid >> 4;
    int c = (tid & 15) * 8;
    const float* srcq = qkv + ((size_t)(b * SLEN + i0 + r)) * 768 + h * 128 + c;
    float4 v0 = *(const float4*)(srcq);
    float4 v1 = *(const float4*)(srcq + 4);
    *(float4*)&Qs[r][c]     = v0;
    *(float4*)&Qs[r][c + 4] = v1;
  }

  const float scale = 0.08838834764831845f;    // 1/sqrt(128)

  // ---- scores ----
  for (int jb = 0; jb < cnt; jb += 32) {
    __syncthreads();
    for (int idx = tid * 4; idx < 32 * 128; idx += 1024) {
      int r = idx >> 7, c = idx & 127;
      int j = jmin + jb + r;
      float4 v = (j <= jmax)
        ? *(const float4*)(qkv + ((size_t)(b * SLEN + j)) * 768 + 256 + h * 128 + c)
        : make_float4(0.f, 0.f, 0.f, 0.f);
      *(float4*)&Ks[r][c] = v;
    }
    __syncthreads();
    int qi = tid >> 4;
    int i  = i0 + qi;
#pragma unroll
    for (int half = 0; half < 2; ++half) {
      int jj = (tid & 15) + half * 16;
      int j  = jmin + jb + jj;
      float s = -1e30f;
      if (j <= i && j >= i - WIN) {
        float a = 0.f;
#pragma unroll
        for (int kk = 0; kk < 128; kk += 4) {
          float4 qv = *(const float4*)&Qs[qi][kk];
          float4 kv = *(const float4*)&Ks[jj][kk];
          a += qv.x * kv.x + qv.y * kv.y + qv.z * kv.z + qv.w * kv.w;
        }
        s = a * scale;
      }
      ps[qi][jb + jj] = s;
    }
  }
  __syncthreads();

  // ---- softmax (16 lanes per row, contiguous within a wave) ----
  {
    int r = tid >> 4, sub = tid & 15;
    float m = -1e30f;
    for (int j = sub; j < cntR; j += 16) m = fmaxf(m, ps[r][j]);
#pragma unroll
    for (int off = 8; off; off >>= 1) m = fmaxf(m, __shfl_xor(m, off, 16));
    float sum = 0.f;
    for (int j = sub; j < cntR; j += 16) {
      float e = __expf(ps[r][j] - m);
      ps[r][j] = e;
      sum += e;
    }
#pragma unroll
    for (int off = 8; off; off >>= 1) sum += __shfl_xor(sum, off, 16);
    if (sub == 0) rinv[r] = 1.f / sum;
  }

  // ---- P @ V ----
  float acc[8];
#pragma unroll
  for (int q = 0; q < 8; ++q) acc[q] = 0.f;
  int d     = tid & 127;
  int qbase = (tid >> 7) * 8;
  for (int jb = 0; jb < cnt; jb += 32) {
    __syncthreads();
    for (int idx = tid * 4; idx < 32 * 128; idx += 1024) {
      int r = idx >> 7, c = idx & 127;
      int j = jmin + jb + r;
      float4 v = (j <= jmax)
        ? *(const float4*)(qkv + ((size_t)(b * SLEN + j)) * 768 + 512 + h * 128 + c)
        : make_float4(0.f, 0.f, 0.f, 0.f);
      *(float4*)&Ks[r][c] = v;
    }
    __syncthreads();
    int jcnt = min(32, cntR - jb);               // multiple of 4
    for (int jj = 0; jj < jcnt; jj += 4) {
      float v0 = Ks[jj + 0][d], v1 = Ks[jj + 1][d];
      float v2 = Ks[jj + 2][d], v3 = Ks[jj + 3][d];
#pragma unroll
      for (int q = 0; q < 8; ++q) {
        float4 p = *(const float4*)&ps[qbase + q][jb + jj];
        acc[q] += p.x * v0 + p.y * v1 + p.z * v2 + p.w * v3;
      }
    }
  }
#pragma unroll
  for (int q = 0; q < 8; ++q) {
    int i = i0 + qbase + q;
    ctx[((size_t)(b * SLEN + i)) * 256 + h * 128 + d] = acc[q] * rinv[qbase + q];
  }
}

// ---------------- layernorm in-place over D=256, one block per token ----
__global__ __launch_bounds__(256) void k_ln(float* __restrict__ X,
                                            const float* __restrict__ w,
                                            const float* __restrict__ b) {
  __shared__ float red[8];
  int m = blockIdx.x, tid = threadIdx.x;
  float v = X[(size_t)m * 256 + tid];
  float s = v, q = v * v;
#pragma unroll
  for (int off = 32; off; off >>= 1) {
    s += __shfl_xor(s, off);
    q += __shfl_xor(q, off);
  }
  int wv = tid >> 6;
  if ((tid & 63) == 0) { red[wv] = s; red[4 + wv] = q; }
  __syncthreads();
  s = red[0] + red[1] + red[2] + red[3];
  q = red[4] + red[5] + red[6] + red[7];
  float mu  = s * (1.f / 256.f);
  float var = q * (1.f / 256.f) - mu * mu;
  float r   = rsqrtf(var + 1e-5f);
  X[(size_t)m * 256 + tid] = (v - mu) * r * w[tid] + b[tid];
}

// ---- head prep: the head has NO activation between fc1 and fc2, so
// logits = LN2(x)·w_eff + b_eff with w_eff = fc2·fc1 (a [256] vector).
// Folding LN2's affine in:  logit = r·(Σ v·c1 − μ·Σc1) + c0,
//   c1[k] = ln2_w[k]·w_eff[k];  c0 = Σ ln2_b·w_eff + fc2·fc1_b + fc2_b.
// hp[0..255]=c1, hp[256]=c0, hp[257]=Σc1. One block of 256 threads.
__global__ __launch_bounds__(256) void k_headprep(const float* __restrict__ fc1w,
                                                  const float* __restrict__ fc1b,
                                                  const float* __restrict__ fc2w,
                                                  const float* __restrict__ fc2b,
                                                  const float* __restrict__ ln2w,
                                                  const float* __restrict__ ln2b,
                                                  float* __restrict__ hp) {
  __shared__ float red0[4], red1[4];
  int k = threadIdx.x;
  float we = 0.f;
#pragma unroll 8
  for (int o = 0; o < 64; ++o) we += fc2w[o] * fc1w[o * 256 + k];
  float c1 = ln2w[k] * we;
  hp[k] = c1;
  float p0 = ln2b[k] * we;
  if (k < 64) p0 += fc2w[k] * fc1b[k];
  float s0 = p0, s1 = c1;
#pragma unroll
  for (int off = 32; off; off >>= 1) {
    s0 += __shfl_xor(s0, off);
    s1 += __shfl_xor(s1, off);
  }
  int wv = k >> 6;
  if ((k & 63) == 0) { red0[wv] = s0; red1[wv] = s1; }
  __syncthreads();
  if (k == 0) {
    hp[256] = red0[0] + red0[1] + red0[2] + red0[3] + fc2b[0];
    hp[257] = red1[0] + red1[1] + red1[2] + red1[3];
  }
}

// ---- fused LN2 + head: one wave per token, coalesced float4 read of x.
// Never materializes x2. block 256 = 4 waves = 4 tokens.
__global__ __launch_bounds__(256) void k_ln2head(const float* __restrict__ X,
                                                 const float* __restrict__ hp,
                                                 float* __restrict__ out) {
  __shared__ float c1s[256];
  int tid = threadIdx.x;
  c1s[tid] = hp[tid];
  __syncthreads();
  int w = tid >> 6, lane = tid & 63;
  int m = blockIdx.x * 4 + w;
  const float* row = X + (size_t)m * 256;
  float4 v = *(const float4*)(row + lane * 4);
  float4 c = *(const float4*)&c1s[lane * 4];
  float s = v.x + v.y + v.z + v.w;
  float q = v.x * v.x + v.y * v.y + v.z * v.z + v.w * v.w;
  float d = v.x * c.x + v.y * c.y + v.z * c.z + v.w * c.w;
#pragma unroll
  for (int off = 32; off; off >>= 1) {
    s += __shfl_xor(s, off);
    q += __shfl_xor(q, off);
    d += __shfl_xor(d, off);
  }
  if (lane == 0) {
    float mu  = s * (1.f / 256.f);
    float var = q * (1.f / 256.f) - mu * mu;
    float r   = rsqrtf(var + 1e-5f);
    out[m] = r * (d - mu * hp[257]) + hp[256];
  }
}

extern "C" void kernel_launch(void* const* d_in, const int* in_sizes, int n_in,
                              void* d_out, int out_size, void* d_ws, size_t ws_size,
                              hipStream_t stream) {
  const float* src        = (const float*)d_in[0];
  // d_in[1] = input_lengths (int64) — unused by the reference computation
  const float* W_enc      = (const float*)d_in[2];
  const float* b_enc      = (const float*)d_in[3];
  const float* in_proj_w  = (const float*)d_in[4];
  const float* in_proj_b  = (const float*)d_in[5];
  const float* out_proj_w = (const float*)d_in[6];
  const float* out_proj_b = (const float*)d_in[7];
  const float* ln1_w      = (const float*)d_in[8];
  const float* ln1_b      = (const float*)d_in[9];
  const float* lin1_w     = (const float*)d_in[10];
  const float* lin1_b     = (const float*)d_in[11];
  const float* lin2_w     = (const float*)d_in[12];
  const float* lin2_b     = (const float*)d_in[13];
  const float* ln2_w      = (const float*)d_in[14];
  const float* ln2_b      = (const float*)d_in[15];
  const float* fc1_w      = (const float*)d_in[16];
  const float* fc1_b      = (const float*)d_in[17];
  const float* fc2_w      = (const float*)d_in[18];
  const float* fc2_b      = (const float*)d_in[19];

  float* ws  = (float*)d_ws;
  float* x   = ws;                      // [16000][256]
  float* qkv = x + (size_t)MTOK * 256;  // [16000][768]   (later reused as x1)
  float* ctx = qkv + (size_t)MTOK * 768;// [16000][256]   (later reused as ffn hidden)
  float* pe  = ctx + (size_t)MTOK * 256;// [2000][256]
  float* hp  = pe + (size_t)SLEN * 256; // [258] head-prep constants

  k_posenc<<<SLEN * 256 / 256, 256, 0, stream>>>(pe);
  k_headprep<<<1, 256, 0, stream>>>(fc1_w, fc1_b, fc2_w, fc2_b, ln2_w, ln2_b, hp);
  // x = src @ W_enc^T + b_enc + posenc
  k_gemm<<<dim3(MTOK / 128, 2), 256, 0, stream>>>(src, W_enc, b_enc, x, pe, 256, EPI_POSENC);
  // qkv = x @ in_proj^T + b
  k_gemm<<<dim3(MTOK / 128, 6), 256, 0, stream>>>(x, in_proj_w, in_proj_b, qkv, nullptr, 768, EPI_NONE);
  // banded attention -> ctx
  k_attn<<<dim3(SLEN / 16, BATCH, 2), 256, 0, stream>>>(qkv, ctx);
  // pre-LN1 = ctx @ out_proj^T + b + x   (written into qkv buffer, reused as x1)
  k_gemm<<<dim3(MTOK / 128, 2), 256, 0, stream>>>(ctx, out_proj_w, out_proj_b, qkv, x, 256, EPI_RESID);
  k_ln<<<MTOK, 256, 0, stream>>>(qkv, ln1_w, ln1_b);                 // x1 (in-place)
  // h = relu(x1 @ lin1^T + b)  -> ctx buffer
  k_gemm<<<dim3(MTOK / 128, 2), 256, 0, stream>>>(qkv, lin1_w, lin1_b, ctx, nullptr, 256, EPI_RELU);
  // pre-LN2 = h @ lin2^T + b + x1 -> x buffer
  k_gemm<<<dim3(MTOK / 128, 2), 256, 0, stream>>>(ctx, lin2_w, lin2_b, x, qkv, 256, EPI_RESID);
  // fused LN2 + collapsed head (x2 never materialized)
  k_ln2head<<<MTOK / 4, 256, 0, stream>>>(x, hp, (float*)d_out);
}

// Round 4
// 299.591 us; speedup vs baseline: 1.8425x; 1.4092x over previous
//
#include <hip/hip_runtime.h>
#include <math.h>

#define SLEN 2000
#define BATCH 8
#define MTOK 16000
#define WIN 99

enum { EPI_NONE = 0, EPI_POSENC = 1, EPI_RELU = 2, EPI_RESID = 3 };

typedef __attribute__((ext_vector_type(8))) short short8;
typedef __attribute__((ext_vector_type(4))) float floatx4;

// ---------- bf16 helpers (bit-level, RNE) ----------
__device__ __forceinline__ float bf2f(unsigned int h) {
  union { unsigned int u; float f; } w; w.u = h << 16; return w.f;
}
__device__ __forceinline__ unsigned short f2bf(float f) {
  union { float f; unsigned int u; } w; w.f = f;
  return (unsigned short)((w.u + 0x7fffu + ((w.u >> 16) & 1u)) >> 16);
}
__device__ __forceinline__ void unpack8(uint4 u, float* o) {
  o[0] = bf2f(u.x & 0xffffu); o[1] = bf2f(u.x >> 16);
  o[2] = bf2f(u.y & 0xffffu); o[3] = bf2f(u.y >> 16);
  o[4] = bf2f(u.z & 0xffffu); o[5] = bf2f(u.z >> 16);
  o[6] = bf2f(u.w & 0xffffu); o[7] = bf2f(u.w >> 16);
}

// async global->LDS, 16B per lane; lds base must be wave-uniform
typedef const __attribute__((address_space(1))) unsigned int* gas_t;
typedef __attribute__((address_space(3))) unsigned int* las_t;
__device__ __forceinline__ void gload_lds16(const unsigned short* g, unsigned short* l) {
  __builtin_amdgcn_global_load_lds((gas_t)g, (las_t)l, 16, 0, 0);
}

// ---------------- fp32 -> bf16 cast (grid-stride by float4) ----------------
__global__ __launch_bounds__(256) void k_cvt(const float* __restrict__ in,
                                             unsigned short* __restrict__ out, int n4) {
  int i = blockIdx.x * 256 + threadIdx.x;
  if (i < n4) {
    float4 v = ((const float4*)in)[i];
    ushort4 o;
    o.x = f2bf(v.x); o.y = f2bf(v.y); o.z = f2bf(v.z); o.w = f2bf(v.w);
    ((ushort4*)out)[i] = o;
  }
}

// ---------------- positional encoding table [SLEN][256] fp32 ----------------
__global__ __launch_bounds__(256) void k_posenc(float* __restrict__ pe) {
  int idx = blockIdx.x * 256 + threadIdx.x;
  int s = idx >> 8;
  int d = idx & 255;
  int p = d >> 1;
  float dv  = expf((float)p * -0.07195578415606394f);  // exp(-p*ln(10000)/128)
  float ang = (float)s * dv;
  pe[idx] = (d & 1) ? cosf(ang) : sinf(ang);
}

// ---- MFMA GEMM: Y[M,N](bf16) = A[M,256](bf16) @ B[N,256](bf16)^T + bias(f32)
// 128x128 tile, 4 waves as 2x2 of 64x64, each wave 4x4 mfma_f32_16x16x32_bf16.
// LDS tiles [128 rows][32 k] bf16, 16B chunks XOR-swizzled by (row>>1)&3 so
// ds_read_b128 frag reads are 2-way (free) and global_load_lds stays
// lane-order contiguous. K staged in 8 chunks of 32.
__global__ __launch_bounds__(256) void k_gemm_mfma(
    const unsigned short* __restrict__ A,
    const unsigned short* __restrict__ B,
    const float* __restrict__ bias,
    unsigned short* __restrict__ Y,
    const float* __restrict__ pe,
    const unsigned short* __restrict__ resid,
    int N, int mode) {
  __shared__ __align__(16) unsigned short As[128 * 32];
  __shared__ __align__(16) unsigned short Bs[128 * 32];
  const int tid  = threadIdx.x;
  const int lane = tid & 63;
  const int w    = tid >> 6;
  const int wrow = (w >> 1) * 64;
  const int wcol = (w & 1) * 64;
  const int m0 = blockIdx.x * 128;
  const int o0 = blockIdx.y * 128;

  floatx4 acc[4][4] = {};

  // staging: wave w issues LDS pieces i=2w,2w+1 (each 1KB = 16 rows x 64B)
  const int i0i = w * 2, i1i = w * 2 + 1;
  const int sr0 = i0i * 16 + (lane >> 2);
  const int sr1 = i1i * 16 + (lane >> 2);
  const int ss  = lane & 3;                    // stored 16B-slot in row
  const int sc0 = ss ^ ((sr0 >> 1) & 3);       // real k-chunk fetched
  const int sc1 = ss ^ ((sr1 >> 1) & 3);
  const unsigned short* ag0 = A + (size_t)(m0 + sr0) * 256 + sc0 * 8;
  const unsigned short* ag1 = A + (size_t)(m0 + sr1) * 256 + sc1 * 8;
  const unsigned short* bg0 = B + (size_t)(o0 + sr0) * 256 + sc0 * 8;
  const unsigned short* bg1 = B + (size_t)(o0 + sr1) * 256 + sc1 * 8;
  unsigned short* al0 = &As[i0i * 512];
  unsigned short* al1 = &As[i1i * 512];
  unsigned short* bl0 = &Bs[i0i * 512];
  unsigned short* bl1 = &Bs[i1i * 512];

  const int kq = lane >> 4;   // k-quad (8 bf16) for A/B frags
  const int ml = lane & 15;   // row within 16-tile

  for (int kt = 0; kt < 256; kt += 32) {
    __syncthreads();
    gload_lds16(ag0 + kt, al0);
    gload_lds16(ag1 + kt, al1);
    gload_lds16(bg0 + kt, bl0);
    gload_lds16(bg1 + kt, bl1);
    __syncthreads();   // compiler drains vmcnt before s_barrier

    short8 af[4], bf[4];
#pragma unroll
    for (int t = 0; t < 4; ++t) {
      int m  = wrow + t * 16 + ml;
      int sa = kq ^ ((m >> 1) & 3);
      af[t] = *(const short8*)&As[m * 32 + sa * 8];
      int n  = wcol + t * 16 + ml;
      int sb = kq ^ ((n >> 1) & 3);
      bf[t] = *(const short8*)&Bs[n * 32 + sb * 8];
    }
#pragma unroll
    for (int mt = 0; mt < 4; ++mt)
#pragma unroll
      for (int nt = 0; nt < 4; ++nt)
        acc[mt][nt] = __builtin_amdgcn_mfma_f32_16x16x32_bf16(
            af[mt], bf[nt], acc[mt][nt], 0, 0, 0);
  }

  // epilogue: C/D layout col=lane&15, row=(lane>>4)*4+reg  [m89]
  const int cq = lane >> 4, cl = lane & 15;
#pragma unroll
  for (int mt = 0; mt < 4; ++mt) {
#pragma unroll
    for (int nt = 0; nt < 4; ++nt) {
#pragma unroll
      for (int r = 0; r < 4; ++r) {
        int row = m0 + wrow + mt * 16 + cq * 4 + r;
        int col = o0 + wcol + nt * 16 + cl;
        float v = acc[mt][nt][r] + bias[col];
        if (mode == EPI_POSENC)     v += pe[(size_t)(row % SLEN) * 256 + col];
        else if (mode == EPI_RELU)  v = fmaxf(v, 0.f);
        else if (mode == EPI_RESID) v += bf2f(resid[(size_t)row * 256 + col]);
        Y[(size_t)row * N + col] = f2bf(v);
      }
    }
  }
}

// ---------------- banded attention (bf16 qkv in, bf16 ctx out) ----------------
// grid (S/16, B, H), block 256. qkv layout: [b][s][768] bf16.
__global__ __launch_bounds__(256) void k_attn(const unsigned short* __restrict__ qkv,
                                              unsigned short* __restrict__ ctx) {
  __shared__ float Qs[16][132];
  __shared__ float Ks[32][132];          // reused for V chunks
  __shared__ float ps[16][128];
  __shared__ float rinv[16];
  const int tid = threadIdx.x;
  const int i0  = blockIdx.x * 16;
  const int b   = blockIdx.y;
  const int h   = blockIdx.z;

  const int jmin = max(0, i0 - WIN);
  const int jmax = i0 + 15;
  const int cnt  = jmax - jmin + 1;            // <= 115
  const int cntR = (cnt + 3) & ~3;

  // load Q tile (16x128)
  {
    int r = tid >> 4;
    int c = (tid & 15) * 8;
    uint4 u = *(const uint4*)(qkv + ((size_t)(b * SLEN + i0 + r)) * 768 + h * 128 + c);
    float f[8]; unpack8(u, f);
#pragma unroll
    for (int t = 0; t < 8; ++t) Qs[r][c + t] = f[t];
  }

  const float scale = 0.08838834764831845f;    // 1/sqrt(128)

  // ---- scores ----
  for (int jb = 0; jb < cnt; jb += 32) {
    __syncthreads();
    for (int idx = tid * 8; idx < 32 * 128; idx += 2048) {
      int r = idx >> 7, c = idx & 127;
      int j = jmin + jb + r;
      float f[8];
      if (j <= jmax) {
        uint4 u = *(const uint4*)(qkv + ((size_t)(b * SLEN + j)) * 768 + 256 + h * 128 + c);
        unpack8(u, f);
      } else {
#pragma unroll
        for (int t = 0; t < 8; ++t) f[t] = 0.f;
      }
#pragma unroll
      for (int t = 0; t < 8; ++t) Ks[r][c + t] = f[t];
    }
    __syncthreads();
    int qi = tid >> 4;
    int i  = i0 + qi;
#pragma unroll
    for (int half = 0; half < 2; ++half) {
      int jj = (tid & 15) + half * 16;
      int j  = jmin + jb + jj;
      float s = -1e30f;
      if (j <= i && j >= i - WIN) {
        float a = 0.f;
#pragma unroll
        for (int kk = 0; kk < 128; kk += 4) {
          float4 qv = *(const float4*)&Qs[qi][kk];
          float4 kv = *(const float4*)&Ks[jj][kk];
          a += qv.x * kv.x + qv.y * kv.y + qv.z * kv.z + qv.w * kv.w;
        }
        s = a * scale;
      }
      ps[qi][jb + jj] = s;
    }
  }
  __syncthreads();

  // ---- softmax (16 lanes per row) ----
  {
    int r = tid >> 4, sub = tid & 15;
    float m = -1e30f;
    for (int j = sub; j < cntR; j += 16) m = fmaxf(m, ps[r][j]);
#pragma unroll
    for (int off = 8; off; off >>= 1) m = fmaxf(m, __shfl_xor(m, off, 16));
    float sum = 0.f;
    for (int j = sub; j < cntR; j += 16) {
      float e = __expf(ps[r][j] - m);
      ps[r][j] = e;
      sum += e;
    }
#pragma unroll
    for (int off = 8; off; off >>= 1) sum += __shfl_xor(sum, off, 16);
    if (sub == 0) rinv[r] = 1.f / sum;
  }

  // ---- P @ V ----
  float acc[8];
#pragma unroll
  for (int q = 0; q < 8; ++q) acc[q] = 0.f;
  int d     = tid & 127;
  int qbase = (tid >> 7) * 8;
  for (int jb = 0; jb < cnt; jb += 32) {
    __syncthreads();
    for (int idx = tid * 8; idx < 32 * 128; idx += 2048) {
      int r = idx >> 7, c = idx & 127;
      int j = jmin + jb + r;
      float f[8];
      if (j <= jmax) {
        uint4 u = *(const uint4*)(qkv + ((size_t)(b * SLEN + j)) * 768 + 512 + h * 128 + c);
        unpack8(u, f);
      } else {
#pragma unroll
        for (int t = 0; t < 8; ++t) f[t] = 0.f;
      }
#pragma unroll
      for (int t = 0; t < 8; ++t) Ks[r][c + t] = f[t];
    }
    __syncthreads();
    int jcnt = min(32, cntR - jb);               // multiple of 4
    for (int jj = 0; jj < jcnt; jj += 4) {
      float v0 = Ks[jj + 0][d], v1 = Ks[jj + 1][d];
      float v2 = Ks[jj + 2][d], v3 = Ks[jj + 3][d];
#pragma unroll
      for (int q = 0; q < 8; ++q) {
        float4 p = *(const float4*)&ps[qbase + q][jb + jj];
        acc[q] += p.x * v0 + p.y * v1 + p.z * v2 + p.w * v3;
      }
    }
  }
#pragma unroll
  for (int q = 0; q < 8; ++q) {
    int i = i0 + qbase + q;
    ctx[((size_t)(b * SLEN + i)) * 256 + h * 128 + d] = f2bf(acc[q] * rinv[qbase + q]);
  }
}

// ---------------- layernorm in-place over D=256 (bf16 io, fp32 math) ----
__global__ __launch_bounds__(256) void k_ln(unsigned short* __restrict__ X,
                                            const float* __restrict__ w,
                                            const float* __restrict__ b) {
  __shared__ float red[8];
  int m = blockIdx.x, tid = threadIdx.x;
  float v = bf2f(X[(size_t)m * 256 + tid]);
  float s = v, q = v * v;
#pragma unroll
  for (int off = 32; off; off >>= 1) {
    s += __shfl_xor(s, off);
    q += __shfl_xor(q, off);
  }
  int wv = tid >> 6;
  if ((tid & 63) == 0) { red[wv] = s; red[4 + wv] = q; }
  __syncthreads();
  s = red[0] + red[1] + red[2] + red[3];
  q = red[4] + red[5] + red[6] + red[7];
  float mu  = s * (1.f / 256.f);
  float var = q * (1.f / 256.f) - mu * mu;
  float r   = rsqrtf(var + 1e-5f);
  X[(size_t)m * 256 + tid] = f2bf((v - mu) * r * w[tid] + b[tid]);
}

// ---- head prep: logits = LN2(x)·c1-terms; see R1 derivation ----
__global__ __launch_bounds__(256) void k_headprep(const float* __restrict__ fc1w,
                                                  const float* __restrict__ fc1b,
                                                  const float* __restrict__ fc2w,
                                                  const float* __restrict__ fc2b,
                                                  const float* __restrict__ ln2w,
                                                  const float* __restrict__ ln2b,
                                                  float* __restrict__ hp) {
  __shared__ float red0[4], red1[4];
  int k = threadIdx.x;
  float we = 0.f;
#pragma unroll 8
  for (int o = 0; o < 64; ++o) we += fc2w[o] * fc1w[o * 256 + k];
  float c1 = ln2w[k] * we;
  hp[k] = c1;
  float p0 = ln2b[k] * we;
  if (k < 64) p0 += fc2w[k] * fc1b[k];
  float s0 = p0, s1 = c1;
#pragma unroll
  for (int off = 32; off; off >>= 1) {
    s0 += __shfl_xor(s0, off);
    s1 += __shfl_xor(s1, off);
  }
  int wv = k >> 6;
  if ((k & 63) == 0) { red0[wv] = s0; red1[wv] = s1; }
  __syncthreads();
  if (k == 0) {
    hp[256] = red0[0] + red0[1] + red0[2] + red0[3] + fc2b[0];
    hp[257] = red1[0] + red1[1] + red1[2] + red1[3];
  }
}

// ---- fused LN2 + collapsed head: one wave per token, bf16 x in ----
__global__ __launch_bounds__(256) void k_ln2head(const unsigned short* __restrict__ X,
                                                 const float* __restrict__ hp,
                                                 float* __restrict__ out) {
  __shared__ float c1s[256];
  int tid = threadIdx.x;
  c1s[tid] = hp[tid];
  __syncthreads();
  int w = tid >> 6, lane = tid & 63;
  int m = blockIdx.x * 4 + w;
  uint2 u = *(const uint2*)(X + (size_t)m * 256 + lane * 4);
  float v0 = bf2f(u.x & 0xffffu), v1 = bf2f(u.x >> 16);
  float v2 = bf2f(u.y & 0xffffu), v3 = bf2f(u.y >> 16);
  float4 c = *(const float4*)&c1s[lane * 4];
  float s = v0 + v1 + v2 + v3;
  float q = v0 * v0 + v1 * v1 + v2 * v2 + v3 * v3;
  float d = v0 * c.x + v1 * c.y + v2 * c.z + v3 * c.w;
#pragma unroll
  for (int off = 32; off; off >>= 1) {
    s += __shfl_xor(s, off);
    q += __shfl_xor(q, off);
    d += __shfl_xor(d, off);
  }
  if (lane == 0) {
    float mu  = s * (1.f / 256.f);
    float var = q * (1.f / 256.f) - mu * mu;
    float r   = rsqrtf(var + 1e-5f);
    out[m] = r * (d - mu * hp[257]) + hp[256];
  }
}

extern "C" void kernel_launch(void* const* d_in, const int* in_sizes, int n_in,
                              void* d_out, int out_size, void* d_ws, size_t ws_size,
                              hipStream_t stream) {
  const float* src        = (const float*)d_in[0];
  // d_in[1] = input_lengths (unused)
  const float* W_enc      = (const float*)d_in[2];
  const float* b_enc      = (const float*)d_in[3];
  const float* in_proj_w  = (const float*)d_in[4];
  const float* in_proj_b  = (const float*)d_in[5];
  const float* out_proj_w = (const float*)d_in[6];
  const float* out_proj_b = (const float*)d_in[7];
  const float* ln1_w      = (const float*)d_in[8];
  const float* ln1_b      = (const float*)d_in[9];
  const float* lin1_w     = (const float*)d_in[10];
  const float* lin1_b     = (const float*)d_in[11];
  const float* lin2_w     = (const float*)d_in[12];
  const float* lin2_b     = (const float*)d_in[13];
  const float* ln2_w      = (const float*)d_in[14];
  const float* ln2_b      = (const float*)d_in[15];
  const float* fc1_w      = (const float*)d_in[16];
  const float* fc1_b      = (const float*)d_in[17];
  const float* fc2_w      = (const float*)d_in[18];
  const float* fc2_b      = (const float*)d_in[19];

  char* p = (char*)d_ws;
  float* pe            = (float*)p;           p += (size_t)SLEN * 256 * 4;
  float* hp            = (float*)p;           p += 2048;  // 258 floats used; was 1024 -> hp[256..257] clobbered by srcb (R3 bug)
  unsigned short* srcb = (unsigned short*)p;  p += (size_t)MTOK * 256 * 2;
  unsigned short* xb   = (unsigned short*)p;  p += (size_t)MTOK * 256 * 2;
  unsigned short* qkvb = (unsigned short*)p;  p += (size_t)MTOK * 768 * 2;
  unsigned short* ctxb = (unsigned short*)p;  p += (size_t)MTOK * 256 * 2;
  unsigned short* x1b  = (unsigned short*)p;  p += (size_t)MTOK * 256 * 2;
  unsigned short* wencb= (unsigned short*)p;  p += 256 * 256 * 2;
  unsigned short* wqkb = (unsigned short*)p;  p += 768 * 256 * 2;
  unsigned short* woutb= (unsigned short*)p;  p += 256 * 256 * 2;
  unsigned short* wl1b = (unsigned short*)p;  p += 256 * 256 * 2;
  unsigned short* wl2b = (unsigned short*)p;  p += 256 * 256 * 2;
  // total ~60.3 MB

  k_posenc<<<SLEN, 256, 0, stream>>>(pe);
  k_headprep<<<1, 256, 0, stream>>>(fc1_w, fc1_b, fc2_w, fc2_b, ln2_w, ln2_b, hp);

  auto cvt = [&](const float* in, unsigned short* out, int n) {
    int n4 = n / 4;
    k_cvt<<<(n4 + 255) / 256, 256, 0, stream>>>(in, out, n4);
  };
  cvt(src,        srcb,  MTOK * 256);
  cvt(W_enc,      wencb, 256 * 256);
  cvt(in_proj_w,  wqkb,  768 * 256);
  cvt(out_proj_w, woutb, 256 * 256);
  cvt(lin1_w,     wl1b,  256 * 256);
  cvt(lin2_w,     wl2b,  256 * 256);

  // x = src @ W_enc^T + b + posenc
  k_gemm_mfma<<<dim3(MTOK / 128, 2), 256, 0, stream>>>(srcb, wencb, b_enc, xb, pe, nullptr, 256, EPI_POSENC);
  // qkv = x @ in_proj^T + b
  k_gemm_mfma<<<dim3(MTOK / 128, 6), 256, 0, stream>>>(xb, wqkb, in_proj_b, qkvb, nullptr, nullptr, 768, EPI_NONE);
  // banded attention
  k_attn<<<dim3(SLEN / 16, BATCH, 2), 256, 0, stream>>>(qkvb, ctxb);
  // pre-LN1 = ctx @ out_proj^T + b + x
  k_gemm_mfma<<<dim3(MTOK / 128, 2), 256, 0, stream>>>(ctxb, woutb, out_proj_b, x1b, nullptr, xb, 256, EPI_RESID);
  k_ln<<<MTOK, 256, 0, stream>>>(x1b, ln1_w, ln1_b);
  // h = relu(x1 @ lin1^T + b)
  k_gemm_mfma<<<dim3(MTOK / 128, 2), 256, 0, stream>>>(x1b, wl1b, lin1_b, ctxb, nullptr, nullptr, 256, EPI_RELU);
  // pre-LN2 = h @ lin2^T + b + x1  (into xb, reused)
  k_gemm_mfma<<<dim3(MTOK / 128, 2), 256, 0, stream>>>(ctxb, wl2b, lin2_b, xb, nullptr, x1b, 256, EPI_RESID);
  // fused LN2 + collapsed head
  k_ln2head<<<MTOK / 4, 256, 0, stream>>>(xb, hp, (float*)d_out);
}

// Round 5
// 233.208 us; speedup vs baseline: 2.3670x; 1.2847x over previous
//
#include <hip/hip_runtime.h>
#include <math.h>

#define SLEN 2000
#define BATCH 8
#define MTOK 16000
#define WIN 99

enum { EPI_NONE = 0, EPI_POSENC = 1, EPI_RELU = 2, EPI_RESID = 3 };

typedef __attribute__((ext_vector_type(8))) short short8;
typedef __attribute__((ext_vector_type(4))) float floatx4;

// ---------- bf16 helpers (bit-level, RNE) ----------
__device__ __forceinline__ float bf2f(unsigned int h) {
  union { unsigned int u; float f; } w; w.u = h << 16; return w.f;
}
__device__ __forceinline__ unsigned short f2bf(float f) {
  union { float f; unsigned int u; } w; w.f = f;
  return (unsigned short)((w.u + 0x7fffu + ((w.u >> 16) & 1u)) >> 16);
}

// async global->LDS, 16B per lane; lds base must be wave-uniform
typedef const __attribute__((address_space(1))) unsigned int* gas_t;
typedef __attribute__((address_space(3))) unsigned int* las_t;
__device__ __forceinline__ void gload_lds16(const unsigned short* g, unsigned short* l) {
  __builtin_amdgcn_global_load_lds((gas_t)g, (las_t)l, 16, 0, 0);
}

// ================= fused prep: src-cvt + 5 weight-cvts + posenc + headprep =================
// one launch replaces 8; block ranges select the job (block-uniform branches).
__device__ __forceinline__ void cvt4(const float* __restrict__ in,
                                     unsigned short* __restrict__ out, int i) {
  float4 v = ((const float4*)in)[i];
  ushort4 o;
  o.x = f2bf(v.x); o.y = f2bf(v.y); o.z = f2bf(v.z); o.w = f2bf(v.w);
  ((ushort4*)out)[i] = o;
}

__global__ __launch_bounds__(256) void k_prep(
    const float* __restrict__ src,      unsigned short* __restrict__ srcb,
    const float* __restrict__ wenc,     unsigned short* __restrict__ wencb,
    const float* __restrict__ wqk,      unsigned short* __restrict__ wqkb,
    const float* __restrict__ wout,     unsigned short* __restrict__ woutb,
    const float* __restrict__ wl1,      unsigned short* __restrict__ wl1b,
    const float* __restrict__ wl2,      unsigned short* __restrict__ wl2b,
    float* __restrict__ pe,
    const float* __restrict__ fc1w, const float* __restrict__ fc1b,
    const float* __restrict__ fc2w, const float* __restrict__ fc2b,
    const float* __restrict__ ln2w, const float* __restrict__ ln2b,
    float* __restrict__ hp) {
  __shared__ float red0[4], red1[4];
  const int bx = blockIdx.x, tid = threadIdx.x;
  if (bx < 4000)       { cvt4(src,  srcb,  bx * 256 + tid); }            // 1,024,000 f4
  else if (bx < 4064)  { cvt4(wenc, wencb, (bx - 4000) * 256 + tid); }
  else if (bx < 4256)  { cvt4(wqk,  wqkb,  (bx - 4064) * 256 + tid); }
  else if (bx < 4320)  { cvt4(wout, woutb, (bx - 4256) * 256 + tid); }
  else if (bx < 4384)  { cvt4(wl1,  wl1b,  (bx - 4320) * 256 + tid); }
  else if (bx < 4448)  { cvt4(wl2,  wl2b,  (bx - 4384) * 256 + tid); }
  else if (bx < 6448) {                                                   // posenc
    int idx = (bx - 4448) * 256 + tid;
    int s = idx >> 8, d = idx & 255, p2 = d >> 1;
    float dv  = expf((float)p2 * -0.07195578415606394f);
    float ang = (float)s * dv;
    pe[idx] = (d & 1) ? cosf(ang) : sinf(ang);
  } else {                                                                // headprep (1 block)
    int k = tid;
    float we = 0.f;
#pragma unroll 8
    for (int o = 0; o < 64; ++o) we += fc2w[o] * fc1w[o * 256 + k];
    float c1 = ln2w[k] * we;
    hp[k] = c1;
    float p0 = ln2b[k] * we;
    if (k < 64) p0 += fc2w[k] * fc1b[k];
    float s0 = p0, s1 = c1;
#pragma unroll
    for (int off = 32; off; off >>= 1) {
      s0 += __shfl_xor(s0, off);
      s1 += __shfl_xor(s1, off);
    }
    int wv = k >> 6;
    if ((k & 63) == 0) { red0[wv] = s0; red1[wv] = s1; }
    __syncthreads();
    if (k == 0) {
      hp[256] = red0[0] + red0[1] + red0[2] + red0[3] + fc2b[0];
      hp[257] = red1[0] + red1[1] + red1[2] + red1[3];
    }
  }
}

// ---- MFMA GEMM: Y[M,N](bf16) = A[M,256](bf16) @ B[N,256](bf16)^T + bias(f32)
// (unchanged from R4 — verified)
__global__ __launch_bounds__(256) void k_gemm_mfma(
    const unsigned short* __restrict__ A,
    const unsigned short* __restrict__ B,
    const float* __restrict__ bias,
    unsigned short* __restrict__ Y,
    const float* __restrict__ pe,
    const unsigned short* __restrict__ resid,
    int N, int mode) {
  __shared__ __align__(16) unsigned short As[128 * 32];
  __shared__ __align__(16) unsigned short Bs[128 * 32];
  const int tid  = threadIdx.x;
  const int lane = tid & 63;
  const int w    = tid >> 6;
  const int wrow = (w >> 1) * 64;
  const int wcol = (w & 1) * 64;
  const int m0 = blockIdx.x * 128;
  const int o0 = blockIdx.y * 128;

  floatx4 acc[4][4] = {};

  const int i0i = w * 2, i1i = w * 2 + 1;
  const int sr0 = i0i * 16 + (lane >> 2);
  const int sr1 = i1i * 16 + (lane >> 2);
  const int ss  = lane & 3;
  const int sc0 = ss ^ ((sr0 >> 1) & 3);
  const int sc1 = ss ^ ((sr1 >> 1) & 3);
  const unsigned short* ag0 = A + (size_t)(m0 + sr0) * 256 + sc0 * 8;
  const unsigned short* ag1 = A + (size_t)(m0 + sr1) * 256 + sc1 * 8;
  const unsigned short* bg0 = B + (size_t)(o0 + sr0) * 256 + sc0 * 8;
  const unsigned short* bg1 = B + (size_t)(o0 + sr1) * 256 + sc1 * 8;
  unsigned short* al0 = &As[i0i * 512];
  unsigned short* al1 = &As[i1i * 512];
  unsigned short* bl0 = &Bs[i0i * 512];
  unsigned short* bl1 = &Bs[i1i * 512];

  const int kq = lane >> 4;
  const int ml = lane & 15;

  for (int kt = 0; kt < 256; kt += 32) {
    __syncthreads();
    gload_lds16(ag0 + kt, al0);
    gload_lds16(ag1 + kt, al1);
    gload_lds16(bg0 + kt, bl0);
    gload_lds16(bg1 + kt, bl1);
    __syncthreads();

    short8 af[4], bf[4];
#pragma unroll
    for (int t = 0; t < 4; ++t) {
      int m  = wrow + t * 16 + ml;
      int sa = kq ^ ((m >> 1) & 3);
      af[t] = *(const short8*)&As[m * 32 + sa * 8];
      int n  = wcol + t * 16 + ml;
      int sb = kq ^ ((n >> 1) & 3);
      bf[t] = *(const short8*)&Bs[n * 32 + sb * 8];
    }
#pragma unroll
    for (int mt = 0; mt < 4; ++mt)
#pragma unroll
      for (int nt = 0; nt < 4; ++nt)
        acc[mt][nt] = __builtin_amdgcn_mfma_f32_16x16x32_bf16(
            af[mt], bf[nt], acc[mt][nt], 0, 0, 0);
  }

  const int cq = lane >> 4, cl = lane & 15;
#pragma unroll
  for (int mt = 0; mt < 4; ++mt) {
#pragma unroll
    for (int nt = 0; nt < 4; ++nt) {
#pragma unroll
      for (int r = 0; r < 4; ++r) {
        int row = m0 + wrow + mt * 16 + cq * 4 + r;
        int col = o0 + wcol + nt * 16 + cl;
        float v = acc[mt][nt][r] + bias[col];
        if (mode == EPI_POSENC)     v += pe[(size_t)(row % SLEN) * 256 + col];
        else if (mode == EPI_RELU)  v = fmaxf(v, 0.f);
        else if (mode == EPI_RESID) v += bf2f(resid[(size_t)row * 256 + col]);
        Y[(size_t)row * N + col] = f2bf(v);
      }
    }
  }
}

// ================= MFMA banded attention =================
// grid (ceil(S/64), B, H), block 256 = 4 waves. Wave w: queries [i0+16w, i0+16w+15],
// private 128-key window at offset 16w into the 176-key staged union [i0-99, i0+76].
// Phase 1: K staged row-major (KPAD=136) -> QK^T (32 mfma/wave) -> softmax in
// C-layout regs -> P(bf16) to LDS. Phase 2: V transpose-staged into the SAME
// buffer (Vt[d][key], VPAD=184) -> PV (32 mfma/wave) -> scale by 1/sum -> ctx.
// LDS = 176*136*2 + 4*16*132*2 = 64.7... -> 47872 + 16896 = 63.3 KB (2 blocks/CU).
#define KPAD 136
#define VPAD 184
#define PPAD 132
#define UNION 176

__global__ __launch_bounds__(256) void k_attn_mfma(const unsigned short* __restrict__ qkv,
                                                   unsigned short* __restrict__ ctx) {
  __shared__ __align__(16) unsigned short KV[UNION * KPAD];   // K phase 1, Vt phase 2
  __shared__ __align__(16) unsigned short Ps[4][16 * PPAD];
  const int tid  = threadIdx.x;
  const int lane = tid & 63;
  const int w    = tid >> 6;
  const int i0   = blockIdx.x * 64;
  const int b    = blockIdx.y;
  const int h    = blockIdx.z;
  const int jmin_u = i0 - WIN;                 // global j of staged slot 0
  const float scale = 0.08838834764831845f;    // 1/sqrt(128)

  // ---- Q fragments straight from global (A-operand: m=lane&15, k=(lane>>4)*8+j) ----
  const int qrow = i0 + w * 16 + (lane & 15);
  const unsigned short* qptr =
      qkv + (size_t)(b * SLEN + min(qrow, SLEN - 1)) * 768 + h * 128 + (lane >> 4) * 8;
  short8 qf[4];
#pragma unroll
  for (int kc = 0; kc < 4; ++kc) qf[kc] = *(const short8*)(qptr + kc * 32);

  // ---- stage K: 176 rows x 128 bf16, row-major, stride KPAD ----
  for (int it = 0; it < 11; ++it) {
    int idx = it * 256 + tid;            // 176*16 = 2816 = 11*256 exact
    int row = idx >> 4;
    int c8  = idx & 15;
    int j = jmin_u + row;
    uint4 v = make_uint4(0u, 0u, 0u, 0u);
    if (j >= 0 && j < SLEN)
      v = *(const uint4*)(qkv + (size_t)(b * SLEN + j) * 768 + 256 + h * 128 + c8 * 8);
    *(uint4*)&KV[row * KPAD + c8 * 8] = v;
  }
  __syncthreads();

  // ---- QK^T: 8 key-tiles x 4 k-chunks ----
  const int koff = w * 16;                     // wave key offset in union
  floatx4 sc[8] = {};
#pragma unroll
  for (int kt = 0; kt < 8; ++kt) {
#pragma unroll
    for (int kc = 0; kc < 4; ++kc) {
      short8 kf = *(const short8*)&KV[(koff + kt * 16 + (lane & 15)) * KPAD
                                      + kc * 32 + (lane >> 4) * 8];
      sc[kt] = __builtin_amdgcn_mfma_f32_16x16x32_bf16(qf[kc], kf, sc[kt], 0, 0, 0);
    }
  }

  // ---- mask + softmax in C-layout (row q = (lane>>4)*4+r lives in a 16-lane group) ----
  const int qme = i0 + w * 16 + (lane >> 4) * 4;     // + r
  const int jme = jmin_u + koff + (lane & 15);       // + kt*16
  float mx[4] = {-1e30f, -1e30f, -1e30f, -1e30f};
#pragma unroll
  for (int kt = 0; kt < 8; ++kt) {
#pragma unroll
    for (int r = 0; r < 4; ++r) {
      int j = jme + kt * 16, q = qme + r;
      bool ok = (j >= 0) && (j >= q - WIN) && (j <= q);
      float s = ok ? sc[kt][r] : -1e30f;
      sc[kt][r] = s;
      mx[r] = fmaxf(mx[r], s);
    }
  }
#pragma unroll
  for (int r = 0; r < 4; ++r)
#pragma unroll
    for (int off = 8; off; off >>= 1) mx[r] = fmaxf(mx[r], __shfl_xor(mx[r], off, 16));

  float sum[4] = {0.f, 0.f, 0.f, 0.f};
#pragma unroll
  for (int kt = 0; kt < 8; ++kt)
#pragma unroll
    for (int r = 0; r < 4; ++r) {
      float e = __expf((sc[kt][r] - mx[r]) * scale);
      sc[kt][r] = e;
      sum[r] += e;
    }
#pragma unroll
  for (int r = 0; r < 4; ++r)
#pragma unroll
    for (int off = 8; off; off >>= 1) sum[r] += __shfl_xor(sum[r], off, 16);
  float rinv[4];
#pragma unroll
  for (int r = 0; r < 4; ++r) rinv[r] = 1.f / sum[r];

  // ---- P (bf16) to LDS ----
  unsigned short* pw = &Ps[w][0];
#pragma unroll
  for (int kt = 0; kt < 8; ++kt)
#pragma unroll
    for (int r = 0; r < 4; ++r)
      pw[((lane >> 4) * 4 + r) * PPAD + kt * 16 + (lane & 15)] = f2bf(sc[kt][r]);
  __syncthreads();   // all waves done reading K before Vt overwrites the buffer

  // ---- stage V transposed: Vt[d][key], stride VPAD (keys across lanes -> 2-way banks) ----
  for (int it = 0; it < 12; ++it) {
    int idx = it * 256 + tid;            // 48 groups of 64 lanes
    int grp = idx >> 6;                  // 0..47
    int key = (grp >> 4) * 64 + (idx & 63);
    int c8  = grp & 15;
    if (key < UNION) {
      int j = jmin_u + key;
      uint4 v = make_uint4(0u, 0u, 0u, 0u);
      if (j >= 0 && j < SLEN)
        v = *(const uint4*)(qkv + (size_t)(b * SLEN + j) * 768 + 512 + h * 128 + c8 * 8);
      unsigned short e[8];
      *(uint4*)e = v;
      int d0 = c8 * 8;
#pragma unroll
      for (int i = 0; i < 8; ++i) KV[(d0 + i) * VPAD + key] = e[i];
    }
  }
  __syncthreads();

  // ---- PV: A = P, B = Vt rows ----
  floatx4 ov[8] = {};
#pragma unroll
  for (int kc = 0; kc < 4; ++kc) {
    short8 pf = *(const short8*)&pw[(lane & 15) * PPAD + kc * 32 + (lane >> 4) * 8];
#pragma unroll
    for (int dt = 0; dt < 8; ++dt) {
      short8 vf = *(const short8*)&KV[(dt * 16 + (lane & 15)) * VPAD
                                      + koff + kc * 32 + (lane >> 4) * 8];
      ov[dt] = __builtin_amdgcn_mfma_f32_16x16x32_bf16(pf, vf, ov[dt], 0, 0, 0);
    }
  }

  // ---- store ctx (C-layout rows match rinv's lane rows) ----
#pragma unroll
  for (int dt = 0; dt < 8; ++dt)
#pragma unroll
    for (int r = 0; r < 4; ++r) {
      int q = qme + r;
      if (q < SLEN)
        ctx[(size_t)(b * SLEN + q) * 256 + h * 128 + dt * 16 + (lane & 15)] =
            f2bf(ov[dt][r] * rinv[r]);
    }
}

// ---------------- layernorm in-place over D=256 (bf16 io, fp32 math) ----
__global__ __launch_bounds__(256) void k_ln(unsigned short* __restrict__ X,
                                            const float* __restrict__ w,
                                            const float* __restrict__ b) {
  __shared__ float red[8];
  int m = blockIdx.x, tid = threadIdx.x;
  float v = bf2f(X[(size_t)m * 256 + tid]);
  float s = v, q = v * v;
#pragma unroll
  for (int off = 32; off; off >>= 1) {
    s += __shfl_xor(s, off);
    q += __shfl_xor(q, off);
  }
  int wv = tid >> 6;
  if ((tid & 63) == 0) { red[wv] = s; red[4 + wv] = q; }
  __syncthreads();
  s = red[0] + red[1] + red[2] + red[3];
  q = red[4] + red[5] + red[6] + red[7];
  float mu  = s * (1.f / 256.f);
  float var = q * (1.f / 256.f) - mu * mu;
  float r   = rsqrtf(var + 1e-5f);
  X[(size_t)m * 256 + tid] = f2bf((v - mu) * r * w[tid] + b[tid]);
}

// ---- fused LN2 + collapsed head: one wave per token, bf16 x in ----
__global__ __launch_bounds__(256) void k_ln2head(const unsigned short* __restrict__ X,
                                                 const float* __restrict__ hp,
                                                 float* __restrict__ out) {
  __shared__ float c1s[256];
  int tid = threadIdx.x;
  c1s[tid] = hp[tid];
  __syncthreads();
  int w = tid >> 6, lane = tid & 63;
  int m = blockIdx.x * 4 + w;
  uint2 u = *(const uint2*)(X + (size_t)m * 256 + lane * 4);
  float v0 = bf2f(u.x & 0xffffu), v1 = bf2f(u.x >> 16);
  float v2 = bf2f(u.y & 0xffffu), v3 = bf2f(u.y >> 16);
  float4 c = *(const float4*)&c1s[lane * 4];
  float s = v0 + v1 + v2 + v3;
  float q = v0 * v0 + v1 * v1 + v2 * v2 + v3 * v3;
  float d = v0 * c.x + v1 * c.y + v2 * c.z + v3 * c.w;
#pragma unroll
  for (int off = 32; off; off >>= 1) {
    s += __shfl_xor(s, off);
    q += __shfl_xor(q, off);
    d += __shfl_xor(d, off);
  }
  if (lane == 0) {
    float mu  = s * (1.f / 256.f);
    float var = q * (1.f / 256.f) - mu * mu;
    float r   = rsqrtf(var + 1e-5f);
    out[m] = r * (d - mu * hp[257]) + hp[256];
  }
}

extern "C" void kernel_launch(void* const* d_in, const int* in_sizes, int n_in,
                              void* d_out, int out_size, void* d_ws, size_t ws_size,
                              hipStream_t stream) {
  const float* src        = (const float*)d_in[0];
  // d_in[1] = input_lengths (unused)
  const float* W_enc      = (const float*)d_in[2];
  const float* b_enc      = (const float*)d_in[3];
  const float* in_proj_w  = (const float*)d_in[4];
  const float* in_proj_b  = (const float*)d_in[5];
  const float* out_proj_w = (const float*)d_in[6];
  const float* out_proj_b = (const float*)d_in[7];
  const float* ln1_w      = (const float*)d_in[8];
  const float* ln1_b      = (const float*)d_in[9];
  const float* lin1_w     = (const float*)d_in[10];
  const float* lin1_b     = (const float*)d_in[11];
  const float* lin2_w     = (const float*)d_in[12];
  const float* lin2_b     = (const float*)d_in[13];
  const float* ln2_w      = (const float*)d_in[14];
  const float* ln2_b      = (const float*)d_in[15];
  const float* fc1_w      = (const float*)d_in[16];
  const float* fc1_b      = (const float*)d_in[17];
  const float* fc2_w      = (const float*)d_in[18];
  const float* fc2_b      = (const float*)d_in[19];

  char* p = (char*)d_ws;
  float* pe            = (float*)p;           p += (size_t)SLEN * 256 * 4;
  float* hp            = (float*)p;           p += 2048;   // 258 floats used
  unsigned short* srcb = (unsigned short*)p;  p += (size_t)MTOK * 256 * 2;
  unsigned short* xb   = (unsigned short*)p;  p += (size_t)MTOK * 256 * 2;
  unsigned short* qkvb = (unsigned short*)p;  p += (size_t)MTOK * 768 * 2;
  unsigned short* ctxb = (unsigned short*)p;  p += (size_t)MTOK * 256 * 2;
  unsigned short* x1b  = (unsigned short*)p;  p += (size_t)MTOK * 256 * 2;
  unsigned short* wencb= (unsigned short*)p;  p += 256 * 256 * 2;
  unsigned short* wqkb = (unsigned short*)p;  p += 768 * 256 * 2;
  unsigned short* woutb= (unsigned short*)p;  p += 256 * 256 * 2;
  unsigned short* wl1b = (unsigned short*)p;  p += 256 * 256 * 2;
  unsigned short* wl2b = (unsigned short*)p;  p += 256 * 256 * 2;

  // one fused prep launch: src cvt (4000) + 5 weight cvts (448) + posenc (2000) + headprep (1)
  k_prep<<<6449, 256, 0, stream>>>(src, srcb, W_enc, wencb, in_proj_w, wqkb,
                                   out_proj_w, woutb, lin1_w, wl1b, lin2_w, wl2b,
                                   pe, fc1_w, fc1_b, fc2_w, fc2_b, ln2_w, ln2_b, hp);

  // x = src @ W_enc^T + b + posenc
  k_gemm_mfma<<<dim3(MTOK / 128, 2), 256, 0, stream>>>(srcb, wencb, b_enc, xb, pe, nullptr, 256, EPI_POSENC);
  // qkv = x @ in_proj^T + b
  k_gemm_mfma<<<dim3(MTOK / 128, 6), 256, 0, stream>>>(xb, wqkb, in_proj_b, qkvb, nullptr, nullptr, 768, EPI_NONE);
  // banded attention (MFMA)
  k_attn_mfma<<<dim3((SLEN + 63) / 64, BATCH, 2), 256, 0, stream>>>(qkvb, ctxb);
  // pre-LN1 = ctx @ out_proj^T + b + x
  k_gemm_mfma<<<dim3(MTOK / 128, 2), 256, 0, stream>>>(ctxb, woutb, out_proj_b, x1b, nullptr, xb, 256, EPI_RESID);
  k_ln<<<MTOK, 256, 0, stream>>>(x1b, ln1_w, ln1_b);
  // h = relu(x1 @ lin1^T + b)
  k_gemm_mfma<<<dim3(MTOK / 128, 2), 256, 0, stream>>>(x1b, wl1b, lin1_b, ctxb, nullptr, nullptr, 256, EPI_RELU);
  // pre-LN2 = h @ lin2^T + b + x1  (into xb, reused)
  k_gemm_mfma<<<dim3(MTOK / 128, 2), 256, 0, stream>>>(ctxb, wl2b, lin2_b, xb, nullptr, x1b, 256, EPI_RESID);
  // fused LN2 + collapsed head
  k_ln2head<<<MTOK / 4, 256, 0, stream>>>(xb, hp, (float*)d_out);
}

// Round 6
// 174.372 us; speedup vs baseline: 3.1657x; 1.3374x over previous
//
#include <hip/hip_runtime.h>
#include <math.h>

#define SLEN 2000
#define BATCH 8
#define MTOK 16000
#define WIN 99

typedef __attribute__((ext_vector_type(8))) short short8;
typedef __attribute__((ext_vector_type(4))) float floatx4;

// ---------- bf16 helpers (bit-level, RNE) ----------
__device__ __forceinline__ float bf2f(unsigned int h) {
  union { unsigned int u; float f; } w; w.u = h << 16; return w.f;
}
__device__ __forceinline__ unsigned short f2bf(float f) {
  union { float f; unsigned int u; } w; w.f = f;
  return (unsigned short)((w.u + 0x7fffu + ((w.u >> 16) & 1u)) >> 16);
}

// async global->LDS, 16B per lane; lds base must be wave-uniform
typedef const __attribute__((address_space(1))) unsigned int* gas_t;
typedef __attribute__((address_space(3))) unsigned int* las_t;
__device__ __forceinline__ void gload_lds16(const unsigned short* g, unsigned short* l) {
  __builtin_amdgcn_global_load_lds((gas_t)g, (las_t)l, 16, 0, 0);
}

// ================= prep: 5 weight cvts + posenc + headprep =================
__device__ __forceinline__ void cvt4(const float* __restrict__ in,
                                     unsigned short* __restrict__ out, int i) {
  float4 v = ((const float4*)in)[i];
  ushort4 o;
  o.x = f2bf(v.x); o.y = f2bf(v.y); o.z = f2bf(v.z); o.w = f2bf(v.w);
  ((ushort4*)out)[i] = o;
}

__global__ __launch_bounds__(256) void k_prep(
    const float* __restrict__ wenc,     unsigned short* __restrict__ wencb,
    const float* __restrict__ wqk,      unsigned short* __restrict__ wqkb,
    const float* __restrict__ wout,     unsigned short* __restrict__ woutb,
    const float* __restrict__ wl1,      unsigned short* __restrict__ wl1b,
    const float* __restrict__ wl2,      unsigned short* __restrict__ wl2b,
    float* __restrict__ pe,
    const float* __restrict__ fc1w, const float* __restrict__ fc1b,
    const float* __restrict__ fc2w, const float* __restrict__ fc2b,
    const float* __restrict__ ln2w, const float* __restrict__ ln2b,
    float* __restrict__ hp) {
  __shared__ float red0[4], red1[4];
  const int bx = blockIdx.x, tid = threadIdx.x;
  if (bx < 64)         { cvt4(wenc, wencb, bx * 256 + tid); }
  else if (bx < 256)   { cvt4(wqk,  wqkb,  (bx - 64) * 256 + tid); }
  else if (bx < 320)   { cvt4(wout, woutb, (bx - 256) * 256 + tid); }
  else if (bx < 384)   { cvt4(wl1,  wl1b,  (bx - 320) * 256 + tid); }
  else if (bx < 448)   { cvt4(wl2,  wl2b,  (bx - 384) * 256 + tid); }
  else if (bx < 2448) {                                                   // posenc
    int idx = (bx - 448) * 256 + tid;
    int s = idx >> 8, d = idx & 255, p2 = d >> 1;
    float dv  = expf((float)p2 * -0.07195578415606394f);
    float ang = (float)s * dv;
    pe[idx] = (d & 1) ? cosf(ang) : sinf(ang);
  } else {                                                                // headprep
    int k = tid;
    float we = 0.f;
#pragma unroll 8
    for (int o = 0; o < 64; ++o) we += fc2w[o] * fc1w[o * 256 + k];
    float c1 = ln2w[k] * we;
    hp[k] = c1;
    float p0 = ln2b[k] * we;
    if (k < 64) p0 += fc2w[k] * fc1b[k];
    float s0 = p0, s1 = c1;
#pragma unroll
    for (int off = 32; off; off >>= 1) {
      s0 += __shfl_xor(s0, off);
      s1 += __shfl_xor(s1, off);
    }
    int wv = k >> 6;
    if ((k & 63) == 0) { red0[wv] = s0; red1[wv] = s1; }
    __syncthreads();
    if (k == 0) {
      hp[256] = red0[0] + red0[1] + red0[2] + red0[3] + fc2b[0];
      hp[257] = red1[0] + red1[1] + red1[2] + red1[3];
    }
  }
}

// ================= fused encoder + qkv projection =================
// 250 blocks x 64 tokens. Wave w owns rows 16w..16w+15, all output cols.
// Stage 1: x = src(fp32)@Wenc^T + b + posenc -> Xt (LDS) + xb (global).
// Stage 2: qkv = Xt@Wqk^T + b (3 passes of 256 cols) -> qkvb.
// LDS staging buffers use the k_gemm XOR-swizzle (slot sc = ss ^ ((row>>1)&3)):
// frag ds_read_b128 lands at 2-way bank aliasing (free). X1/Xt row pad = 8 bf16
// (528B stride: 16B-aligned, rows advance 4 banks -> 2-way, free).
#define XPAD 264

__global__ __launch_bounds__(256) void k_pre(
    const float* __restrict__ src,
    const unsigned short* __restrict__ wenc, const float* __restrict__ benc,
    const float* __restrict__ pe,
    const unsigned short* __restrict__ wqk, const float* __restrict__ bqk,
    unsigned short* __restrict__ xb, unsigned short* __restrict__ qkvb) {
  __shared__ __align__(16) unsigned short Xt[64 * XPAD];     // 33792 B
  __shared__ __align__(16) unsigned short Achk[64 * 32];     // 4096 B
  __shared__ __align__(16) unsigned short Bchk[256 * 32];    // 16384 B
  const int tid = threadIdx.x, lane = tid & 63, w = tid >> 6;
  const int m0 = blockIdx.x * 64;
  const int kq = lane >> 4, ml = lane & 15;
  const int myrow = w * 16 + ml;                     // A-frag row (local)
  const int cq = lane >> 4, cl = lane & 15;          // C-layout

  // A-cvt staging: thread -> (row ar, stored slot as), fetch chunk ac
  const int ar = tid >> 2, as = tid & 3;
  const int ac = as ^ ((ar >> 1) & 3);
  const float* asrc = src + (size_t)(m0 + ar) * 256 + ac * 8;

  // B staging (global_load_lds): wave w, issue i: 16 rows each
  int brow[4], bsc[4];
#pragma unroll
  for (int i = 0; i < 4; ++i) {
    brow[i] = (w * 4 + i) * 16 + (lane >> 2);
    bsc[i]  = (lane & 3) ^ ((brow[i] >> 1) & 3);
  }

  // ---- stage 1: x = src @ Wenc^T ----
  floatx4 acc[16] = {};
  for (int kt = 0; kt < 256; kt += 32) {
    __syncthreads();
    {  // A: fp32 load + cvt + ds_write (swizzled slot)
      float4 v0 = *(const float4*)(asrc + kt);
      float4 v1 = *(const float4*)(asrc + kt + 4);
      unsigned short t8[8] = {f2bf(v0.x), f2bf(v0.y), f2bf(v0.z), f2bf(v0.w),
                              f2bf(v1.x), f2bf(v1.y), f2bf(v1.z), f2bf(v1.w)};
      *(uint4*)&Achk[ar * 32 + as * 8] = *(const uint4*)t8;
    }
#pragma unroll
    for (int i = 0; i < 4; ++i)
      gload_lds16(wenc + (size_t)brow[i] * 256 + kt + bsc[i] * 8, &Bchk[(w * 4 + i) * 512]);
    __syncthreads();

    int sa = kq ^ ((myrow >> 1) & 3);
    short8 af = *(const short8*)&Achk[myrow * 32 + sa * 8];
#pragma unroll
    for (int nt = 0; nt < 16; ++nt) {
      int n = nt * 16 + ml;
      int sb = kq ^ ((n >> 1) & 3);
      short8 bf = *(const short8*)&Bchk[n * 32 + sb * 8];
      acc[nt] = __builtin_amdgcn_mfma_f32_16x16x32_bf16(af, bf, acc[nt], 0, 0, 0);
    }
  }
  // epilogue: + bias + posenc -> Xt (LDS) + xb (global)
#pragma unroll
  for (int nt = 0; nt < 16; ++nt) {
#pragma unroll
    for (int r = 0; r < 4; ++r) {
      int lrow = w * 16 + cq * 4 + r;
      int row  = m0 + lrow;
      int col  = nt * 16 + cl;
      float v = acc[nt][r] + benc[col] + pe[(size_t)(row % SLEN) * 256 + col];
      unsigned short hv = f2bf(v);
      Xt[lrow * XPAD + col] = hv;
      xb[(size_t)row * 256 + col] = hv;
    }
  }

  // ---- stage 2: qkv = Xt @ Wqk^T, 3 passes of 256 cols ----
  for (int p = 0; p < 3; ++p) {
    floatx4 a2[16] = {};
    for (int kt = 0; kt < 256; kt += 32) {
      __syncthreads();
#pragma unroll
      for (int i = 0; i < 4; ++i)
        gload_lds16(wqk + (size_t)(p * 256 + brow[i]) * 256 + kt + bsc[i] * 8,
                    &Bchk[(w * 4 + i) * 512]);
      __syncthreads();
      short8 af = *(const short8*)&Xt[myrow * XPAD + kt + kq * 8];
#pragma unroll
      for (int nt = 0; nt < 16; ++nt) {
        int n = nt * 16 + ml;
        int sb = kq ^ ((n >> 1) & 3);
        short8 bf = *(const short8*)&Bchk[n * 32 + sb * 8];
        a2[nt] = __builtin_amdgcn_mfma_f32_16x16x32_bf16(af, bf, a2[nt], 0, 0, 0);
      }
    }
#pragma unroll
    for (int nt = 0; nt < 16; ++nt) {
#pragma unroll
      for (int r = 0; r < 4; ++r) {
        int row = m0 + w * 16 + cq * 4 + r;
        int cg  = p * 256 + nt * 16 + cl;
        qkvb[(size_t)row * 768 + cg] = f2bf(a2[nt][r] + bqk[cg]);
      }
    }
  }
}

// ================= MFMA banded attention (unchanged from R5 — verified) =================
#define KPAD 136
#define VPAD 184
#define PPAD 132
#define UNION 176

__global__ __launch_bounds__(256) void k_attn_mfma(const unsigned short* __restrict__ qkv,
                                                   unsigned short* __restrict__ ctx) {
  __shared__ __align__(16) unsigned short KV[UNION * KPAD];
  __shared__ __align__(16) unsigned short Ps[4][16 * PPAD];
  const int tid  = threadIdx.x;
  const int lane = tid & 63;
  const int w    = tid >> 6;
  const int i0   = blockIdx.x * 64;
  const int b    = blockIdx.y;
  const int h    = blockIdx.z;
  const int jmin_u = i0 - WIN;
  const float scale = 0.08838834764831845f;

  const int qrow = i0 + w * 16 + (lane & 15);
  const unsigned short* qptr =
      qkv + (size_t)(b * SLEN + min(qrow, SLEN - 1)) * 768 + h * 128 + (lane >> 4) * 8;
  short8 qf[4];
#pragma unroll
  for (int kc = 0; kc < 4; ++kc) qf[kc] = *(const short8*)(qptr + kc * 32);

  for (int it = 0; it < 11; ++it) {
    int idx = it * 256 + tid;
    int row = idx >> 4;
    int c8  = idx & 15;
    int j = jmin_u + row;
    uint4 v = make_uint4(0u, 0u, 0u, 0u);
    if (j >= 0 && j < SLEN)
      v = *(const uint4*)(qkv + (size_t)(b * SLEN + j) * 768 + 256 + h * 128 + c8 * 8);
    *(uint4*)&KV[row * KPAD + c8 * 8] = v;
  }
  __syncthreads();

  const int koff = w * 16;
  floatx4 sc[8] = {};
#pragma unroll
  for (int kt = 0; kt < 8; ++kt) {
#pragma unroll
    for (int kc = 0; kc < 4; ++kc) {
      short8 kf = *(const short8*)&KV[(koff + kt * 16 + (lane & 15)) * KPAD
                                      + kc * 32 + (lane >> 4) * 8];
      sc[kt] = __builtin_amdgcn_mfma_f32_16x16x32_bf16(qf[kc], kf, sc[kt], 0, 0, 0);
    }
  }

  const int qme = i0 + w * 16 + (lane >> 4) * 4;
  const int jme = jmin_u + koff + (lane & 15);
  float mx[4] = {-1e30f, -1e30f, -1e30f, -1e30f};
#pragma unroll
  for (int kt = 0; kt < 8; ++kt) {
#pragma unroll
    for (int r = 0; r < 4; ++r) {
      int j = jme + kt * 16, q = qme + r;
      bool ok = (j >= 0) && (j >= q - WIN) && (j <= q);
      float s = ok ? sc[kt][r] : -1e30f;
      sc[kt][r] = s;
      mx[r] = fmaxf(mx[r], s);
    }
  }
#pragma unroll
  for (int r = 0; r < 4; ++r)
#pragma unroll
    for (int off = 8; off; off >>= 1) mx[r] = fmaxf(mx[r], __shfl_xor(mx[r], off, 16));

  float sum[4] = {0.f, 0.f, 0.f, 0.f};
#pragma unroll
  for (int kt = 0; kt < 8; ++kt)
#pragma unroll
    for (int r = 0; r < 4; ++r) {
      float e = __expf((sc[kt][r] - mx[r]) * scale);
      sc[kt][r] = e;
      sum[r] += e;
    }
#pragma unroll
  for (int r = 0; r < 4; ++r)
#pragma unroll
    for (int off = 8; off; off >>= 1) sum[r] += __shfl_xor(sum[r], off, 16);
  float rinv[4];
#pragma unroll
  for (int r = 0; r < 4; ++r) rinv[r] = 1.f / sum[r];

  unsigned short* pw = &Ps[w][0];
#pragma unroll
  for (int kt = 0; kt < 8; ++kt)
#pragma unroll
    for (int r = 0; r < 4; ++r)
      pw[((lane >> 4) * 4 + r) * PPAD + kt * 16 + (lane & 15)] = f2bf(sc[kt][r]);
  __syncthreads();

  for (int it = 0; it < 12; ++it) {
    int idx = it * 256 + tid;
    int grp = idx >> 6;
    int key = (grp >> 4) * 64 + (idx & 63);
    int c8  = grp & 15;
    if (key < UNION) {
      int j = jmin_u + key;
      uint4 v = make_uint4(0u, 0u, 0u, 0u);
      if (j >= 0 && j < SLEN)
        v = *(const uint4*)(qkv + (size_t)(b * SLEN + j) * 768 + 512 + h * 128 + c8 * 8);
      unsigned short e[8];
      *(uint4*)e = v;
      int d0 = c8 * 8;
#pragma unroll
      for (int i = 0; i < 8; ++i) KV[(d0 + i) * VPAD + key] = e[i];
    }
  }
  __syncthreads();

  floatx4 ov[8] = {};
#pragma unroll
  for (int kc = 0; kc < 4; ++kc) {
    short8 pf = *(const short8*)&pw[(lane & 15) * PPAD + kc * 32 + (lane >> 4) * 8];
#pragma unroll
    for (int dt = 0; dt < 8; ++dt) {
      short8 vf = *(const short8*)&KV[(dt * 16 + (lane & 15)) * VPAD
                                      + koff + kc * 32 + (lane >> 4) * 8];
      ov[dt] = __builtin_amdgcn_mfma_f32_16x16x32_bf16(pf, vf, ov[dt], 0, 0, 0);
    }
  }

#pragma unroll
  for (int dt = 0; dt < 8; ++dt)
#pragma unroll
    for (int r = 0; r < 4; ++r) {
      int q = qme + r;
      if (q < SLEN)
        ctx[(size_t)(b * SLEN + q) * 256 + h * 128 + dt * 16 + (lane & 15)] =
            f2bf(ov[dt][r] * rinv[r]);
    }
}

// ================= fused post-attention chain =================
// 250 blocks x 64 tokens; wave w owns rows 16w..16w+15 (full 256 cols).
// Stage A: ctx@Wout^T + bout + x  -> LN1 (in-wave) -> x1 (LDS + regs)
// Stage B: relu(x1@W1^T + b1)     -> h overwrites x1's LDS
// Stage C: h@W2^T + b2 + x1(regs) -> LN2 + collapsed head -> logits
__global__ __launch_bounds__(256) void k_post(
    const unsigned short* __restrict__ ctx,
    const unsigned short* __restrict__ wout, const float* __restrict__ bout,
    const unsigned short* __restrict__ xb,
    const float* __restrict__ ln1w, const float* __restrict__ ln1b,
    const unsigned short* __restrict__ w1, const float* __restrict__ b1,
    const unsigned short* __restrict__ w2, const float* __restrict__ b2,
    const float* __restrict__ hp, float* __restrict__ out) {
  __shared__ __align__(16) unsigned short X1[64 * XPAD];     // x1, then h
  __shared__ __align__(16) unsigned short Achk[64 * 32];
  __shared__ __align__(16) unsigned short Bchk[256 * 32];
  __shared__ float lnp[512];
  __shared__ float c1s[256];
  const int tid = threadIdx.x, lane = tid & 63, w = tid >> 6;
  const int m0 = blockIdx.x * 64;
  const int kq = lane >> 4, ml = lane & 15;
  const int myrow = w * 16 + ml;
  const int cq = lane >> 4, cl = lane & 15;

  lnp[tid] = ln1w[tid];
  lnp[256 + tid] = ln1b[tid];
  c1s[tid] = hp[tid];
  const float c0 = hp[256], sc1 = hp[257];

  int brow[4], bsc[4];
#pragma unroll
  for (int i = 0; i < 4; ++i) {
    brow[i] = (w * 4 + i) * 16 + (lane >> 2);
    bsc[i]  = (lane & 3) ^ ((brow[i] >> 1) & 3);
  }
  const int arow = w * 16 + (lane >> 2);            // A-chunk staging row
  const int asc  = (lane & 3) ^ ((arow >> 1) & 3);
  const unsigned short* actx = ctx + (size_t)(m0 + arow) * 256 + asc * 8;

  // ---- stage A: ctx @ Wout^T ----
  floatx4 acc[16] = {};
  for (int kt = 0; kt < 256; kt += 32) {
    __syncthreads();
    gload_lds16(actx + kt, &Achk[w * 512]);
#pragma unroll
    for (int i = 0; i < 4; ++i)
      gload_lds16(wout + (size_t)brow[i] * 256 + kt + bsc[i] * 8, &Bchk[(w * 4 + i) * 512]);
    __syncthreads();
    int sa = kq ^ ((myrow >> 1) & 3);
    short8 af = *(const short8*)&Achk[myrow * 32 + sa * 8];
#pragma unroll
    for (int nt = 0; nt < 16; ++nt) {
      int n = nt * 16 + ml;
      int sb = kq ^ ((n >> 1) & 3);
      short8 bf = *(const short8*)&Bchk[n * 32 + sb * 8];
      acc[nt] = __builtin_amdgcn_mfma_f32_16x16x32_bf16(af, bf, acc[nt], 0, 0, 0);
    }
  }
  // epilogue A: + bout + x residual; LN1 stats per row (in-wave)
  float s_[4] = {0.f, 0.f, 0.f, 0.f}, q_[4] = {0.f, 0.f, 0.f, 0.f};
#pragma unroll
  for (int nt = 0; nt < 16; ++nt) {
#pragma unroll
    for (int r = 0; r < 4; ++r) {
      int row = m0 + w * 16 + cq * 4 + r;
      int col = nt * 16 + cl;
      float v = acc[nt][r] + bout[col] + bf2f(xb[(size_t)row * 256 + col]);
      acc[nt][r] = v;
      s_[r] += v;
      q_[r] += v * v;
    }
  }
#pragma unroll
  for (int r = 0; r < 4; ++r)
#pragma unroll
    for (int off = 8; off; off >>= 1) {
      s_[r] += __shfl_xor(s_[r], off, 16);
      q_[r] += __shfl_xor(q_[r], off, 16);
    }
  floatx4 x1sav[16];
#pragma unroll
  for (int r = 0; r < 4; ++r) {
    float mu  = s_[r] * (1.f / 256.f);
    float var = q_[r] * (1.f / 256.f) - mu * mu;
    float rr  = rsqrtf(var + 1e-5f);
    int lrow  = w * 16 + cq * 4 + r;
#pragma unroll
    for (int nt = 0; nt < 16; ++nt) {
      int col = nt * 16 + cl;
      float x1 = (acc[nt][r] - mu) * rr * lnp[col] + lnp[256 + col];
      x1sav[nt][r] = x1;
      X1[lrow * XPAD + col] = f2bf(x1);
    }
  }

  // ---- stage B: h = relu(x1 @ W1^T + b1) ----
#pragma unroll
  for (int nt = 0; nt < 16; ++nt) acc[nt] = (floatx4){0.f, 0.f, 0.f, 0.f};
  for (int kt = 0; kt < 256; kt += 32) {
    __syncthreads();
#pragma unroll
    for (int i = 0; i < 4; ++i)
      gload_lds16(w1 + (size_t)brow[i] * 256 + kt + bsc[i] * 8, &Bchk[(w * 4 + i) * 512]);
    __syncthreads();
    short8 af = *(const short8*)&X1[myrow * XPAD + kt + kq * 8];
#pragma unroll
    for (int nt = 0; nt < 16; ++nt) {
      int n = nt * 16 + ml;
      int sb = kq ^ ((n >> 1) & 3);
      short8 bf = *(const short8*)&Bchk[n * 32 + sb * 8];
      acc[nt] = __builtin_amdgcn_mfma_f32_16x16x32_bf16(af, bf, acc[nt], 0, 0, 0);
    }
  }
  __syncthreads();   // all waves done reading x1 from X1
#pragma unroll
  for (int nt = 0; nt < 16; ++nt) {
#pragma unroll
    for (int r = 0; r < 4; ++r) {
      int lrow = w * 16 + cq * 4 + r;
      int col  = nt * 16 + cl;
      X1[lrow * XPAD + col] = f2bf(fmaxf(acc[nt][r] + b1[col], 0.f));
    }
  }
  __syncthreads();

  // ---- stage C: o = h @ W2^T + b2 + x1; LN2 + head ----
#pragma unroll
  for (int nt = 0; nt < 16; ++nt) acc[nt] = (floatx4){0.f, 0.f, 0.f, 0.f};
  for (int kt = 0; kt < 256; kt += 32) {
    __syncthreads();
#pragma unroll
    for (int i = 0; i < 4; ++i)
      gload_lds16(w2 + (size_t)brow[i] * 256 + kt + bsc[i] * 8, &Bchk[(w * 4 + i) * 512]);
    __syncthreads();
    short8 af = *(const short8*)&X1[myrow * XPAD + kt + kq * 8];
#pragma unroll
    for (int nt = 0; nt < 16; ++nt) {
      int n = nt * 16 + ml;
      int sb = kq ^ ((n >> 1) & 3);
      short8 bf = *(const short8*)&Bchk[n * 32 + sb * 8];
      acc[nt] = __builtin_amdgcn_mfma_f32_16x16x32_bf16(af, bf, acc[nt], 0, 0, 0);
    }
  }
  float ss[4] = {0.f, 0.f, 0.f, 0.f}, qq[4] = {0.f, 0.f, 0.f, 0.f}, dd[4] = {0.f, 0.f, 0.f, 0.f};
#pragma unroll
  for (int nt = 0; nt < 16; ++nt) {
#pragma unroll
    for (int r = 0; r < 4; ++r) {
      int col = nt * 16 + cl;
      float v = acc[nt][r] + b2[col] + x1sav[nt][r];
      ss[r] += v;
      qq[r] += v * v;
      dd[r] += v * c1s[col];
    }
  }
#pragma unroll
  for (int r = 0; r < 4; ++r)
#pragma unroll
    for (int off = 8; off; off >>= 1) {
      ss[r] += __shfl_xor(ss[r], off, 16);
      qq[r] += __shfl_xor(qq[r], off, 16);
      dd[r] += __shfl_xor(dd[r], off, 16);
    }
  if (cl == 0) {
#pragma unroll
    for (int r = 0; r < 4; ++r) {
      float mu  = ss[r] * (1.f / 256.f);
      float var = qq[r] * (1.f / 256.f) - mu * mu;
      float rr  = rsqrtf(var + 1e-5f);
      out[m0 + w * 16 + cq * 4 + r] = rr * (dd[r] - mu * sc1) + c0;
    }
  }
}

extern "C" void kernel_launch(void* const* d_in, const int* in_sizes, int n_in,
                              void* d_out, int out_size, void* d_ws, size_t ws_size,
                              hipStream_t stream) {
  const float* src        = (const float*)d_in[0];
  // d_in[1] = input_lengths (unused)
  const float* W_enc      = (const float*)d_in[2];
  const float* b_enc      = (const float*)d_in[3];
  const float* in_proj_w  = (const float*)d_in[4];
  const float* in_proj_b  = (const float*)d_in[5];
  const float* out_proj_w = (const float*)d_in[6];
  const float* out_proj_b = (const float*)d_in[7];
  const float* ln1_w      = (const float*)d_in[8];
  const float* ln1_b      = (const float*)d_in[9];
  const float* lin1_w     = (const float*)d_in[10];
  const float* lin1_b     = (const float*)d_in[11];
  const float* lin2_w     = (const float*)d_in[12];
  const float* lin2_b     = (const float*)d_in[13];
  const float* ln2_w      = (const float*)d_in[14];
  const float* ln2_b      = (const float*)d_in[15];
  const float* fc1_w      = (const float*)d_in[16];
  const float* fc1_b      = (const float*)d_in[17];
  const float* fc2_w      = (const float*)d_in[18];
  const float* fc2_b      = (const float*)d_in[19];

  char* p = (char*)d_ws;
  float* pe            = (float*)p;           p += (size_t)SLEN * 256 * 4;
  float* hp            = (float*)p;           p += 2048;   // 258 floats used
  unsigned short* xb   = (unsigned short*)p;  p += (size_t)MTOK * 256 * 2;
  unsigned short* qkvb = (unsigned short*)p;  p += (size_t)MTOK * 768 * 2;
  unsigned short* ctxb = (unsigned short*)p;  p += (size_t)MTOK * 256 * 2;
  unsigned short* wencb= (unsigned short*)p;  p += 256 * 256 * 2;
  unsigned short* wqkb = (unsigned short*)p;  p += 768 * 256 * 2;
  unsigned short* woutb= (unsigned short*)p;  p += 256 * 256 * 2;
  unsigned short* wl1b = (unsigned short*)p;  p += 256 * 256 * 2;
  unsigned short* wl2b = (unsigned short*)p;  p += 256 * 256 * 2;

  // prep: 5 weight cvts (448) + posenc (2000) + headprep (1)
  k_prep<<<2449, 256, 0, stream>>>(W_enc, wencb, in_proj_w, wqkb,
                                   out_proj_w, woutb, lin1_w, wl1b, lin2_w, wl2b,
                                   pe, fc1_w, fc1_b, fc2_w, fc2_b, ln2_w, ln2_b, hp);
  // fused encoder + qkv
  k_pre<<<MTOK / 64, 256, 0, stream>>>(src, wencb, b_enc, pe, wqkb, in_proj_b, xb, qkvb);
  // banded attention (MFMA)
  k_attn_mfma<<<dim3((SLEN + 63) / 64, BATCH, 2), 256, 0, stream>>>(qkvb, ctxb);
  // fused out_proj + LN1 + FFN + LN2 + head
  k_post<<<MTOK / 64, 256, 0, stream>>>(ctxb, woutb, out_proj_b, xb, ln1_w, ln1_b,
                                        wl1b, lin1_b, wl2b, lin2_b, hp, (float*)d_out);
}